// Round 8
// baseline (6700.786 us; speedup 1.0000x reference)
//
#include <hip/hip_runtime.h>
#include <math.h>

#define MSZ    1048576ull  // 1024*1024 elements per matrix slot
#define NMAT   33          // matrix 0 = L0, matrices 1..32 = per-batch L
#define PANSZ  114688      // 896*128 shorts per matrix per panel plane
#define NSINK  14

__device__ __forceinline__ float frcp(float x){ return __builtin_amdgcn_rcpf(x); }

typedef __attribute__((ext_vector_type(8)))  short  bfrag;   // 8 x bf16 (4 VGPR)
typedef __attribute__((ext_vector_type(8)))  unsigned short u16x8;
typedef __attribute__((ext_vector_type(16))) float  f32x16;  // 32x32 acc

__device__ __forceinline__ unsigned short bf16rn(float x){
  unsigned u = __float_as_uint(x);
  unsigned r = u + 0x7fffu + ((u>>16)&1u);
  return (unsigned short)(r>>16);
}
__device__ __forceinline__ float bf2f(unsigned short h){
  return __uint_as_float(((unsigned)h)<<16);
}

// ---------------------------------------------------------------- setup
__global__ void k_misc(const float* __restrict__ Vc, float* __restrict__ V,
                       const float* __restrict__ W, float* __restrict__ Ws){
  int t = threadIdx.x;
  if(blockIdx.x < 4){
    int i = blockIdx.x*256 + t;
    float4 v = ((const float4*)Vc)[i];
    float mx = fmaxf(fmaxf(v.x,v.y), fmaxf(v.z,v.w));
    float e0=__expf(v.x-mx), e1=__expf(v.y-mx), e2=__expf(v.z-mx), e3=__expf(v.w-mx);
    float is = 1.f/(e0+e1+e2+e3);
    ((float4*)V)[i] = make_float4(e0*is, e1*is, e2*is, e3*is);
  } else {
    int idx = (blockIdx.x-4)*256 + t;
    int i = idx>>10, j = idx&1023;
    float v = 0.f;
    if(i != j){
      float w = (i>j) ? W[i*1024+j] : W[j*1024+i];
      v = 1.f/(1.f+__expf(-w));
    }
    Ws[idx]=v;
  }
}

__global__ void k_pr_y(const float* __restrict__ V, const int* __restrict__ x,
                       float* __restrict__ PrInv, float* __restrict__ y){
  int b = blockIdx.x, t = threadIdx.x;
  __shared__ float red[256];
  float acc = 0.f;
  for(int i=t; i<1024; i+=256){
    int xv = x[b*1024+i];
    float pr = V[i*4+xv];
    PrInv[b*1024+i] = 1.f/pr;
    acc += logf(pr + 1e-7f);
  }
  red[t]=acc; __syncthreads();
  for(int s=128;s>0;s>>=1){ if(t<s) red[t]+=red[t+s]; __syncthreads(); }
  if(t==0) y[b]=red[0];
}

// ---------------------------------------------------------------- sinkhorn + WP
__global__ void __launch_bounds__(256) k_sinkhorn(
    const float* __restrict__ Ec, const float* __restrict__ V,
    const float* __restrict__ Ws, const float* __restrict__ PrInv,
    const int* __restrict__ x, float* __restrict__ mats,
    float* __restrict__ partial){
  int idx = blockIdx.x*256 + threadIdx.x;
  int i = idx>>10, j = idx&1023;
  if(i==0) return;
  int t = threadIdx.x;
  int lane = t & 63, wv = t >> 6;
  __shared__ float sE[256][17];
  float E[16];
  {
    const float4* p = (const float4*)(Ec + (size_t)idx*16);
    float4 q0=p[0], q1=p[1], q2=p[2], q3=p[3];
    E[0]=__expf(q0.x); E[1]=__expf(q0.y); E[2]=__expf(q0.z); E[3]=__expf(q0.w);
    E[4]=__expf(q1.x); E[5]=__expf(q1.y); E[6]=__expf(q1.z); E[7]=__expf(q1.w);
    E[8]=__expf(q2.x); E[9]=__expf(q2.y); E[10]=__expf(q2.z); E[11]=__expf(q2.w);
    E[12]=__expf(q3.x);E[13]=__expf(q3.y);E[14]=__expf(q3.z); E[15]=__expf(q3.w);
  }
  float s0=0.f;
  #pragma unroll
  for(int q=0;q<16;q++) s0+=E[q];
  float is0 = frcp(s0);
  #pragma unroll
  for(int q=0;q<16;q++) E[q]*=is0;
  float av[4], bv[4];
  {
    float4 va = ((const float4*)V)[i];
    av[0]=va.x; av[1]=va.y; av[2]=va.z; av[3]=va.w;
    float4 vb = ((const float4*)V)[j];
    bv[0]=vb.x; bv[1]=vb.y; bv[2]=vb.z; bv[3]=vb.w;
  }
  for(int it=0; it<NSINK; ++it){
    #pragma unroll
    for(int r=0;r<4;r++){
      float rs = E[4*r]+E[4*r+1]+E[4*r+2]+E[4*r+3];
      float sc = av[r]*frcp(rs+1e-7f);
      E[4*r]*=sc; E[4*r+1]*=sc; E[4*r+2]*=sc; E[4*r+3]*=sc;
    }
    #pragma unroll
    for(int c=0;c<4;c++){
      float cs = E[c]+E[4+c]+E[8+c]+E[12+c];
      float sc = bv[c]*frcp(cs+1e-7f);
      E[c]*=sc; E[4+c]*=sc; E[8+c]*=sc; E[12+c]*=sc;
    }
  }
  #pragma unroll
  for(int q=0;q<16;q++) sE[t][q] = fminf(fmaxf(E[q],0.f),1.f);
  float wsij = Ws[idx];
  for(int b=0;b<32;b++){
    int xi = x[b*1024+i];
    int xj = x[b*1024+j];
    float val = sE[t][(xi<<2)+xj] * wsij * PrInv[b*1024+i] * PrInv[b*1024+j];
    if(j!=0)
      mats[(size_t)(1+b)*MSZ + (size_t)(i-1)*1024 + (j-1)] = 1e-7f - val;
    float r = val;
    r += __shfl_down(r,32); r += __shfl_down(r,16); r += __shfl_down(r,8);
    r += __shfl_down(r,4);  r += __shfl_down(r,2);  r += __shfl_down(r,1);
    if(lane==0)
      partial[((size_t)b<<14) + ((size_t)(i-1)<<4) + ((blockIdx.x&3)<<2) + wv] = r;
  }
}

// ---------------------------------------------------------------- L0 build
__global__ void k_l0(const float* __restrict__ Ws, float* __restrict__ mats){
  int r = blockIdx.x, t = threadIdx.x;
  float* orow = mats + (size_t)r*1024;
  if(r == 1023){
    float4 o = make_float4(0.f,0.f,0.f,0.f);
    if(t==255) o.w = 1.f;
    ((float4*)orow)[t] = o;
    return;
  }
  const float* wrow = Ws + (size_t)(r+1)*1024;
  float4 v = ((const float4*)wrow)[t];
  __shared__ float red[256];
  red[t] = v.x+v.y+v.z+v.w;
  __syncthreads();
  for(int s=128;s>0;s>>=1){ if(t<s) red[t]+=red[t+s]; __syncthreads(); }
  float rs = red[0];
  float o[4];
  #pragma unroll
  for(int q=0;q<4;q++){
    int c = 4*t+q;
    if(c==r)          o[q] = rs + 1e-7f;
    else if(c < 1023) o[q] = 1e-7f - wrow[c+1];
    else              o[q] = 0.f;
  }
  ((float4*)orow)[t] = make_float4(o[0],o[1],o[2],o[3]);
}

__global__ void k_patch(float* __restrict__ mats, const float* __restrict__ partial){
  int m = blockIdx.y + 1;
  int r = blockIdx.x*256 + threadIdx.x;
  float* A = mats + (size_t)m*MSZ;
  A[(size_t)r*1024 + 1023] = (r==1023) ? 1.f : 0.f;
  if(r < 1023){
    A[(size_t)1023*1024 + r] = 0.f;
    const float* pp = partial + (((size_t)(m-1))<<14) + ((size_t)r<<4);
    float s = 0.f;
    #pragma unroll
    for(int q=0;q<16;q++) s += pp[q];
    A[(size_t)r*1024 + r] = s + 1e-7f;
  }
}

// ---------------------------------------------------------- 128x128 diag LU
// LU128 as before (LU64 + panels + Schur + LU64).  NEW inverse tail (R7 was
// 127us: per-lane 128-triangle substitution = O(n^2/2) serial chain with s[128]
// killing reg headroom -> exposed LDS latency).  Blocked inverse instead:
//   Uinv128 = [U11inv, -U11inv*U12*U22inv; 0, U22inv]   (same for L)
// T1: four waves solve ROW-wise 64-triangle inverses (saxpy; distribution
//     reads full contiguous rows as UNIFORM QUADS; pollution lands in dead
//     accumulators).  s[64]+x[64] -> reg headroom, loads pipeline.
// T2: off-diag products as two dense fp32 LDS GEMM passes (1024 FMA/thread,
//     uniform-quad + consecutive-lane reads = the proven-fast Schur pattern).
// Both inverses pack exactly into sm (U upper-incl-diag / L strict-lower).
__global__ void __launch_bounds__(256) k_diag(const float* __restrict__ mats_,
    unsigned short* __restrict__ UiH, unsigned short* __restrict__ UiL,
    unsigned short* __restrict__ LiH, unsigned short* __restrict__ LiL,
    float* __restrict__ logdet, int k, int inv){
  int m = blockIdx.x;
  const float* A = mats_ + (size_t)m*MSZ;
  int t = threadIdx.x, lane = t & 63, w = t >> 6;
  __shared__ float sm[128*128];   // 64 KB

  // load D = A[k:k+128, k:k+128]
  {
    int r = t >> 1, h = (t & 1) * 64;
    const float4* src = (const float4*)(A + (size_t)(k + r)*1024 + k + h);
    float4* dst = (float4*)&sm[r*128 + h];
    #pragma unroll
    for(int q=0;q<16;q++) dst[q] = src[q];
  }
  __syncthreads();

  float slog = 0.f;
  // ---- LU64 on D11 (wave 0, shuffle form)
  if(w==0){
    float row[64];
    #pragma unroll
    for(int q4=0;q4<16;q4++){
      float4 v = *(const float4*)&sm[lane*128 + 4*q4];
      row[4*q4]=v.x; row[4*q4+1]=v.y; row[4*q4+2]=v.z; row[4*q4+3]=v.w;
    }
    #pragma unroll
    for(int c=0;c<64;c++){
      float piv = __shfl(row[c], c);
      slog += logf(fabsf(piv));
      float ip = frcp(piv);
      bool below = lane > c;
      float lic = below ? row[c]*ip : 0.f;
      if(below) row[c] = lic;
      #pragma unroll
      for(int q=c+1;q<64;q++){
        float uq = __shfl(row[q], c);
        row[q] = fmaf(-lic, uq, row[q]);
      }
    }
    #pragma unroll
    for(int q=0;q<64;q++) sm[lane*128+q] = row[q];
  }
  __syncthreads();

  // ---- panel solves, saxpy form (as R7)
  if(w==0){
    float s[64];
    #pragma unroll
    for(int q=0;q<64;q++) s[q]=0.f;
    #pragma unroll
    for(int r=0;r<64;r++){
      float xr = sm[r*128 + 64 + lane] - s[r];
      sm[r*128 + 64 + lane] = xr;
      #pragma unroll
      for(int c=r+1;c<64;c++)
        s[c] = fmaf(sm[c*128 + r], xr, s[c]);
    }
  } else if(w==1){
    float d[64], s[64];
    {
      const float4* src4 = (const float4*)&sm[(64+lane)*128];
      #pragma unroll
      for(int q=0;q<16;q++){
        float4 v=src4[q];
        d[4*q]=v.x; d[4*q+1]=v.y; d[4*q+2]=v.z; d[4*q+3]=v.w;
      }
    }
    #pragma unroll
    for(int q=0;q<64;q++) s[q]=0.f;
    #pragma unroll
    for(int c=0;c<64;c++){
      float xc = (d[c] - s[c]) * frcp(sm[c*128+c]);
      d[c] = xc;
      #pragma unroll
      for(int q=c+1;q<64;q++)
        s[q] = fmaf(sm[c*128+q], xc, s[q]);
    }
    {
      float4* dst4 = (float4*)&sm[(64+lane)*128];
      #pragma unroll
      for(int q=0;q<16;q++)
        dst4[q] = make_float4(d[4*q],d[4*q+1],d[4*q+2],d[4*q+3]);
    }
  }
  __syncthreads();

  // ---- Schur: D22 -= L21*U12
  {
    int j = lane;
    #pragma unroll
    for(int ii=0; ii<16; ii++){
      int i = w*16 + ii;
      float acc2 = sm[(64+i)*128 + 64 + j];
      #pragma unroll
      for(int p=0;p<64;p+=4){
        float4 l4 = *(const float4*)&sm[(64+i)*128 + p];   // uniform
        acc2 = fmaf(-l4.x, sm[(p  )*128 + 64 + j], acc2);
        acc2 = fmaf(-l4.y, sm[(p+1)*128 + 64 + j], acc2);
        acc2 = fmaf(-l4.z, sm[(p+2)*128 + 64 + j], acc2);
        acc2 = fmaf(-l4.w, sm[(p+3)*128 + 64 + j], acc2);
      }
      sm[(64+i)*128 + 64 + j] = acc2;
    }
  }
  __syncthreads();

  // ---- LU64 on updated D22 (wave 0)
  if(w==0){
    float row[64];
    #pragma unroll
    for(int q4=0;q4<16;q4++){
      float4 v = *(const float4*)&sm[(64+lane)*128 + 64 + 4*q4];
      row[4*q4]=v.x; row[4*q4+1]=v.y; row[4*q4+2]=v.z; row[4*q4+3]=v.w;
    }
    #pragma unroll
    for(int c=0;c<64;c++){
      float piv = __shfl(row[c], c);
      slog += logf(fabsf(piv));
      float ip = frcp(piv);
      bool below = lane > c;
      float lic = below ? row[c]*ip : 0.f;
      if(below) row[c] = lic;
      #pragma unroll
      for(int q=c+1;q<64;q++){
        float uq = __shfl(row[q], c);
        row[q] = fmaf(-lic, uq, row[q]);
      }
    }
    #pragma unroll
    for(int q=0;q<64;q++) sm[(64+lane)*128 + 64 + q] = row[q];
    if(lane==0){ if(k==0) logdet[m]=slog; else logdet[m]+=slog; }
  }
  __syncthreads();
  if(!inv) return;

  // ---- T1: row-wise 64-triangle inverses.  lane = row of its triangle.
  // w0: U11inv  w1: U22inv  (x^T U = e_lane^T, c ascending, row quads)
  // w2: L11inv  w3: L22inv  (x^T L = e_lane^T, c descending, row quads)
  {
    float x[64], s[64];
    #pragma unroll
    for(int q=0;q<64;q++){ x[q]=0.f; s[q]=0.f; }
    if(w < 2){
      int b = w*64;
      #pragma unroll
      for(int c=0;c<64;c++){
        float xc = (((c==lane)?1.f:0.f) - s[c]) * frcp(sm[(b+c)*128 + b + c]);
        x[c] = xc;
        #pragma unroll
        for(int q4=0;q4<16;q4++){
          float4 u = *(const float4*)&sm[(b+c)*128 + b + 4*q4];  // uniform quad
          s[4*q4  ] = fmaf(u.x, xc, s[4*q4  ]);
          s[4*q4+1] = fmaf(u.y, xc, s[4*q4+1]);
          s[4*q4+2] = fmaf(u.z, xc, s[4*q4+2]);
          s[4*q4+3] = fmaf(u.w, xc, s[4*q4+3]);
        }
      }
    } else {
      int b = (w-2)*64;
      #pragma unroll
      for(int c=63;c>=0;c--){
        float xc = ((c==lane)?1.f:0.f) - s[c];   // unit diag
        x[c] = xc;
        #pragma unroll
        for(int q4=0;q4<16;q4++){
          float4 u = *(const float4*)&sm[(b+c)*128 + b + 4*q4];  // uniform quad
          s[4*q4  ] = fmaf(u.x, xc, s[4*q4  ]);
          s[4*q4+1] = fmaf(u.y, xc, s[4*q4+1]);
          s[4*q4+2] = fmaf(u.z, xc, s[4*q4+2]);
          s[4*q4+3] = fmaf(u.w, xc, s[4*q4+3]);
        }
      }
    }
    __syncthreads();   // all waves done READING triangles
    // writeback into own triangle (scalar predicated stores; static index)
    if(w < 2){
      int b = w*64;
      #pragma unroll
      for(int c=0;c<64;c++)
        if(c >= lane) sm[(b+lane)*128 + b + c] = x[c];   // upper incl diag
    } else {
      int b = (w-2)*64;
      #pragma unroll
      for(int c=0;c<64;c++)
        if(c < lane) sm[(b+lane)*128 + b + c] = x[c];    // strict lower
    }
  }
  __syncthreads();

  // ---- T2 phase A: T = U12*U22inv -> Q12 ; S = L22inv*L21 -> Q21
  {
    float Ta[16], Sa[16];
    int j = lane;
    #pragma unroll
    for(int ii=0;ii<16;ii++){
      int i = w*16+ii;
      float au=0.f, al=0.f;
      #pragma unroll
      for(int p4=0;p4<16;p4++){
        float4 u12 = *(const float4*)&sm[i*128 + 64 + 4*p4];        // uniform
        float4 l22 = *(const float4*)&sm[(64+i)*128 + 64 + 4*p4];   // uniform
        #pragma unroll
        for(int e=0;e<4;e++){
          int p = 4*p4+e;
          float u12v = (e==0)?u12.x:(e==1)?u12.y:(e==2)?u12.z:u12.w;
          float l22v = (e==0)?l22.x:(e==1)?l22.y:(e==2)?l22.z:l22.w;
          float u22v = sm[(64+p)*128 + 64 + j];   // lanes consecutive
          au = fmaf(u12v, (p<=j)?u22v:0.f, au);
          float lsel = (p<i)?l22v:((p==i)?1.f:0.f);   // uniform select
          al = fmaf(lsel, sm[(64+p)*128 + j], al);    // L21 row p
        }
      }
      Ta[ii]=au; Sa[ii]=al;
    }
    __syncthreads();
    #pragma unroll
    for(int ii=0;ii<16;ii++){
      int i = w*16+ii;
      sm[i*128 + 64 + j] = Ta[ii];        // T -> Q12
      sm[(64+i)*128 + j] = Sa[ii];        // S -> Q21
    }
  }
  __syncthreads();

  // ---- T2 phase B: Q12 = -U11inv*T ; Q21 = -S*L11inv
  {
    float Bu[16], Bl[16];
    int j = lane;
    #pragma unroll
    for(int ii=0;ii<16;ii++){
      int i = w*16+ii;
      float au=0.f, al=0.f;
      #pragma unroll
      for(int p4=0;p4<16;p4++){
        float4 u11 = *(const float4*)&sm[i*128 + 4*p4];          // uniform
        float4 srow = *(const float4*)&sm[(64+i)*128 + 4*p4];    // uniform (S)
        #pragma unroll
        for(int e=0;e<4;e++){
          int p = 4*p4+e;
          float u11v = (e==0)?u11.x:(e==1)?u11.y:(e==2)?u11.z:u11.w;
          float sv   = (e==0)?srow.x:(e==1)?srow.y:(e==2)?srow.z:srow.w;
          au = fmaf((p>=i)?u11v:0.f, sm[p*128 + 64 + j], au);    // T row p
          float lv = sm[p*128 + j];                              // L11inv
          float lsel = (p>j)?lv:((p==j)?1.f:0.f);
          al = fmaf(sv, lsel, al);
        }
      }
      Bu[ii] = -au; Bl[ii] = -al;
    }
    __syncthreads();
    #pragma unroll
    for(int ii=0;ii<16;ii++){
      int i = w*16+ii;
      sm[i*128 + 64 + j] = Bu[ii];
      sm[(64+i)*128 + j] = Bl[ii];
    }
  }
  __syncthreads();

  // ---- emission.  t<128: Uinv col j=t (reads conflict-free row slices).
  //      t>=128: Linv row n=t-128 (row quads).
  if(t < 128){
    int j = t;
    unsigned short* ph = UiH + (size_t)m*16384 + (size_t)j*128;
    unsigned short* pl = UiL + (size_t)m*16384 + (size_t)j*128;
    u16x8 H, L;
    #pragma unroll
    for(int r=0;r<128;r++){
      float v = (r<=j) ? sm[r*128+j] : 0.f;
      unsigned short h = bf16rn(v);
      H[r&7]=h; L[r&7]=bf16rn(v - bf2f(h));
      if((r&7)==7){ ((u16x8*)ph)[r>>3]=H; ((u16x8*)pl)[r>>3]=L; }
    }
  } else {
    int n = t - 128;
    unsigned short* ph = LiH + (size_t)m*16384 + (size_t)n*128;
    unsigned short* pl = LiL + (size_t)m*16384 + (size_t)n*128;
    #pragma unroll
    for(int q=0;q<16;q++){
      float4 u0 = *(const float4*)&sm[n*128 + 8*q];
      float4 u1 = *(const float4*)&sm[n*128 + 8*q + 4];
      float vv[8] = {u0.x,u0.y,u0.z,u0.w,u1.x,u1.y,u1.z,u1.w};
      u16x8 H, L;
      #pragma unroll
      for(int e=0;e<8;e++){
        int c = 8*q+e;
        float v = (c<n) ? vv[e] : ((c==n)?1.f:0.f);
        unsigned short h = bf16rn(v);
        H[e]=h; L[e]=bf16rn(v - bf2f(h));
      }
      ((u16x8*)ph)[q]=H; ((u16x8*)pl)[q]=L;
    }
  }
}

// ---------------------------------------------------------------- MFMA trsm
// K=128.  L21 = A21 * Uinv128 (blockIdx.x < nb), U12^T = A12^T * Linv128^T.
__global__ void __launch_bounds__(256) k_trsm(const float* __restrict__ mats_,
    const unsigned short* __restrict__ UiH, const unsigned short* __restrict__ UiL,
    const unsigned short* __restrict__ LiH, const unsigned short* __restrict__ LiL,
    unsigned short* __restrict__ Ah, unsigned short* __restrict__ Al,
    unsigned short* __restrict__ Bh, unsigned short* __restrict__ Bl,
    int k){
  int m = blockIdx.y;
  const float* A = mats_ + (size_t)m*MSZ;
  int rem = 1024 - (k+128);
  int nb = rem >> 7;
  bool aside = (int)blockIdx.x < nb;
  int t = threadIdx.x, lane = t&63;
  int r32 = lane&31, hi = lane>>5, wv = t>>6;
  int tile0 = (aside ? (int)blockIdx.x : (int)blockIdx.x - nb)*128 + wv*32;
  int rel  = tile0 + r32;

  const unsigned short* IH = (aside ? UiH : LiH) + (size_t)m*16384;
  const unsigned short* IL = (aside ? UiL : LiL) + (size_t)m*16384;

  f32x16 acc[4];
  #pragma unroll
  for(int ct=0;ct<4;ct++)
    #pragma unroll
    for(int q=0;q<16;q++) acc[ct][q]=0.f;

  #pragma unroll
  for(int kc=0;kc<8;kc++){
    float v[8];
    if(aside){
      const float* src = A + (size_t)(k+128+rel)*1024 + k + kc*16 + hi*8;
      float4 u0 = ((const float4*)src)[0];
      float4 u1 = ((const float4*)src)[1];
      v[0]=u0.x; v[1]=u0.y; v[2]=u0.z; v[3]=u0.w;
      v[4]=u1.x; v[5]=u1.y; v[6]=u1.z; v[7]=u1.w;
    } else {
      const float* src = A + (size_t)(k + kc*16 + hi*8)*1024 + (k+128+rel);
      #pragma unroll
      for(int e=0;e<8;e++) v[e] = src[(size_t)e*1024];
    }
    bfrag ah, al;
    #pragma unroll
    for(int e=0;e<8;e++){
      unsigned short h = bf16rn(v[e]);
      ah[e] = (short)h;
      al[e] = (short)bf16rn(v[e] - bf2f(h));
    }
    #pragma unroll
    for(int ct=0;ct<4;ct++){
      bfrag bh = *(const bfrag*)(IH + (size_t)(ct*32+r32)*128 + kc*16 + hi*8);
      bfrag bl = *(const bfrag*)(IL + (size_t)(ct*32+r32)*128 + kc*16 + hi*8);
      acc[ct] = __builtin_amdgcn_mfma_f32_32x32x16_bf16(ah, bh, acc[ct], 0,0,0);
      acc[ct] = __builtin_amdgcn_mfma_f32_32x32x16_bf16(ah, bl, acc[ct], 0,0,0);
      acc[ct] = __builtin_amdgcn_mfma_f32_32x32x16_bf16(al, bh, acc[ct], 0,0,0);
    }
  }

  unsigned short* PH = (aside ? Ah : Bh) + (size_t)m*PANSZ;
  unsigned short* PL = (aside ? Al : Bl) + (size_t)m*PANSZ;
  #pragma unroll
  for(int ct=0;ct<4;ct++){
    #pragma unroll
    for(int reg=0;reg<16;reg++){
      int crow = (reg&3) + ((reg>>2)<<3) + (hi<<2);
      int r = tile0 + crow;
      float v = acc[ct][reg];
      unsigned short h = bf16rn(v);
      size_t off = (size_t)r*128 + ct*32 + r32;
      PH[off] = h;
      PL[off] = bf16rn(v - bf2f(h));
    }
  }
}

// ------------------------------------------------------- MFMA split-bf16 Schur
// A22 -= L21 * U12, K=128 in 4 staged 32-chunks.  128x128 C tile, 4 waves.
__global__ void __launch_bounds__(256) k_gemm(float* __restrict__ mats,
    const unsigned short* __restrict__ Ah, const unsigned short* __restrict__ Al,
    const unsigned short* __restrict__ Bh, const unsigned short* __restrict__ Bl,
    int k){
  int m = blockIdx.z;
  float* A = mats + (size_t)m*MSZ;
  int i0rel = blockIdx.y*128;
  int j0rel = blockIdx.x*128;
  __shared__ unsigned short As[2][4096];   // [hi/lo][row*32 + swz(koct)*8]
  __shared__ unsigned short Bs[2][4096];
  int t = threadIdx.x;
  int lane = t & 63, wvi = t >> 6;
  int wr = wvi >> 1, wc = wvi & 1;

  const unsigned short* pAh = Ah + (size_t)m*PANSZ;
  const unsigned short* pAl = Al + (size_t)m*PANSZ;
  const unsigned short* pBh = Bh + (size_t)m*PANSZ;
  const unsigned short* pBl = Bl + (size_t)m*PANSZ;

  int ldsOff[2];
  size_t offA[2], offB[2];
  #pragma unroll
  for(int p=0;p<2;p++){
    int c = t + 256*p;
    int row = c>>2, koct = c&3;
    ldsOff[p] = row*32 + ((koct ^ ((row>>1)&3))<<3);
    offA[p] = (size_t)(i0rel+row)*128 + koct*8;
    offB[p] = (size_t)(j0rel+row)*128 + koct*8;
  }

  #pragma unroll
  for(int p=0;p<2;p++){
    u16x8 a0 = *(const u16x8*)(pAh + offA[p]);
    u16x8 a1 = *(const u16x8*)(pAl + offA[p]);
    u16x8 b0 = *(const u16x8*)(pBh + offB[p]);
    u16x8 b1 = *(const u16x8*)(pBl + offB[p]);
    *(u16x8*)&As[0][ldsOff[p]] = a0;
    *(u16x8*)&As[1][ldsOff[p]] = a1;
    *(u16x8*)&Bs[0][ldsOff[p]] = b0;
    *(u16x8*)&Bs[1][ldsOff[p]] = b1;
  }
  u16x8 p1[8];
  #pragma unroll
  for(int p=0;p<2;p++){
    p1[4*p+0] = *(const u16x8*)(pAh + offA[p] + 32);
    p1[4*p+1] = *(const u16x8*)(pAl + offA[p] + 32);
    p1[4*p+2] = *(const u16x8*)(pBh + offB[p] + 32);
    p1[4*p+3] = *(const u16x8*)(pBl + offB[p] + 32);
  }
  __syncthreads();

  f32x16 acc[2][2];
  #pragma unroll
  for(int rt=0;rt<2;rt++)
    #pragma unroll
    for(int ct=0;ct<2;ct++)
      #pragma unroll
      for(int q=0;q<16;q++) acc[rt][ct][q] = 0.f;

  int kgrp = lane >> 5;
  #pragma unroll
  for(int st=0; st<4; st++){
    #pragma unroll
    for(int kc=0;kc<2;kc++){
      int koct = kc*2 + kgrp;
      bfrag ah[2], al[2], bh[2], bl[2];
      #pragma unroll
      for(int rt=0;rt<2;rt++){
        int row = wr*64 + rt*32 + (lane&31);
        int ad = row*32 + ((koct ^ ((row>>1)&3))<<3);
        ah[rt] = *(const bfrag*)&As[0][ad];
        al[rt] = *(const bfrag*)&As[1][ad];
      }
      #pragma unroll
      for(int ct=0;ct<2;ct++){
        int col = wc*64 + ct*32 + (lane&31);
        int ad = col*32 + ((koct ^ ((col>>1)&3))<<3);
        bh[ct] = *(const bfrag*)&Bs[0][ad];
        bl[ct] = *(const bfrag*)&Bs[1][ad];
      }
      #pragma unroll
      for(int rt=0;rt<2;rt++)
        #pragma unroll
        for(int ct=0;ct<2;ct++){
          acc[rt][ct] = __builtin_amdgcn_mfma_f32_32x32x16_bf16(ah[rt], bh[ct], acc[rt][ct], 0,0,0);
          acc[rt][ct] = __builtin_amdgcn_mfma_f32_32x32x16_bf16(ah[rt], bl[ct], acc[rt][ct], 0,0,0);
          acc[rt][ct] = __builtin_amdgcn_mfma_f32_32x32x16_bf16(al[rt], bh[ct], acc[rt][ct], 0,0,0);
        }
    }
    if(st<3){
      __syncthreads();
      #pragma unroll
      for(int p=0;p<2;p++){
        *(u16x8*)&As[0][ldsOff[p]] = p1[4*p+0];
        *(u16x8*)&As[1][ldsOff[p]] = p1[4*p+1];
        *(u16x8*)&Bs[0][ldsOff[p]] = p1[4*p+2];
        *(u16x8*)&Bs[1][ldsOff[p]] = p1[4*p+3];
      }
      if(st<2){
        #pragma unroll
        for(int p=0;p<2;p++){
          p1[4*p+0] = *(const u16x8*)(pAh + offA[p] + (st+2)*32);
          p1[4*p+1] = *(const u16x8*)(pAl + offA[p] + (st+2)*32);
          p1[4*p+2] = *(const u16x8*)(pBh + offB[p] + (st+2)*32);
          p1[4*p+3] = *(const u16x8*)(pBl + offB[p] + (st+2)*32);
        }
      }
      __syncthreads();
    }
  }

  int r0 = k + 128;
  #pragma unroll
  for(int rt=0;rt<2;rt++){
    int rowblk = i0rel + wr*64 + rt*32;
    #pragma unroll
    for(int ct=0;ct<2;ct++){
      int colblk = j0rel + wc*64 + ct*32;
      int col = r0 + colblk + (lane&31);
      int rbase = r0 + rowblk + ((lane>>5)<<2);
      #pragma unroll
      for(int reg=0;reg<16;reg++){
        int row = rbase + (reg&3) + ((reg>>2)<<3);
        float* pc = A + (size_t)row*1024 + col;
        *pc -= acc[rt][ct][reg];
      }
    }
  }
}

__global__ void k_final(const float* __restrict__ y, const float* __restrict__ logdet,
                        float* __restrict__ out){
  int b = threadIdx.x;
  if(b<32) out[b] = y[b] + logdet[1+b] - logdet[0];
}

// ---------------------------------------------------------------- launch
extern "C" void kernel_launch(void* const* d_in, const int* in_sizes, int n_in,
                              void* d_out, int out_size, void* d_ws, size_t ws_size,
                              hipStream_t stream){
  (void)in_sizes; (void)n_in; (void)out_size; (void)ws_size;
  const int*   x  = (const int*)d_in[0];
  const float* W  = (const float*)d_in[1];
  const float* Vc = (const float*)d_in[2];
  const float* Ec = (const float*)d_in[3];
  float* out = (float*)d_out;

  char* p = (char*)d_ws;
  auto alloc = [&](size_t bytes)->char*{ char* r = p; p += (bytes+255)&~(size_t)255; return r; };
  float* mats   = (float*)alloc((size_t)NMAT*MSZ*4);              // 138.4 MB
  float* Ws     = (float*)alloc(1048576ull*4);
  unsigned short* Ah = (unsigned short*)alloc((size_t)NMAT*PANSZ*2);
  unsigned short* Al = (unsigned short*)alloc((size_t)NMAT*PANSZ*2);
  unsigned short* Bh = (unsigned short*)alloc((size_t)NMAT*PANSZ*2);
  unsigned short* Bl = (unsigned short*)alloc((size_t)NMAT*PANSZ*2);
  unsigned short* UiH = (unsigned short*)alloc((size_t)NMAT*16384*2);  // 1 MB each
  unsigned short* UiL = (unsigned short*)alloc((size_t)NMAT*16384*2);
  unsigned short* LiH = (unsigned short*)alloc((size_t)NMAT*16384*2);
  unsigned short* LiL = (unsigned short*)alloc((size_t)NMAT*16384*2);
  float* V      = (float*)alloc(4096*4);
  float* PrInv  = (float*)alloc(32768*4);
  float* partial= (float*)alloc((size_t)32*16384*4);              // 2 MB
  float* y      = (float*)alloc(256);
  float* logdet = (float*)alloc(256);

  k_misc<<<4100,256,0,stream>>>(Vc, V, W, Ws);
  k_pr_y<<<32,256,0,stream>>>(V, x, PrInv, y);
  k_sinkhorn<<<4096,256,0,stream>>>(Ec, V, Ws, PrInv, x, mats, partial);
  k_l0<<<1024,256,0,stream>>>(Ws, mats);
  k_patch<<<dim3(4,32),256,0,stream>>>(mats, partial);

  k_diag<<<NMAT,256,0,stream>>>(mats, UiH,UiL,LiH,LiL, logdet, 0, 1);
  for(int s=0;s<7;s++){
    int k = 128*s;
    int rem = 1024 - (k+128);
    int nb = rem/128;
    k_trsm<<<dim3(2*nb,NMAT),256,0,stream>>>(mats, UiH,UiL,LiH,LiL, Ah,Al,Bh,Bl, k);
    k_gemm<<<dim3(nb,nb,NMAT),256,0,stream>>>(mats, Ah,Al,Bh,Bl, k);
    k_diag<<<NMAT,256,0,stream>>>(mats, UiH,UiL,LiH,LiL, logdet, k+128, (s<6)?1:0);
  }
  k_final<<<1,32,0,stream>>>(y, logdet, out);
}

// Round 9
// 5637.788 us; speedup vs baseline: 1.1885x; 1.1885x over previous
//
#include <hip/hip_runtime.h>
#include <math.h>

#define MSZ    1048576ull  // 1024*1024 elements per matrix slot
#define NMAT   33          // matrix 0 = L0, matrices 1..32 = per-batch L
#define PANSZ  114688      // 896*128 shorts per matrix per panel plane
#define NSINK  14

__device__ __forceinline__ float frcp(float x){ return __builtin_amdgcn_rcpf(x); }

typedef __attribute__((ext_vector_type(8)))  short  bfrag;   // 8 x bf16 (4 VGPR)
typedef __attribute__((ext_vector_type(8)))  unsigned short u16x8;
typedef __attribute__((ext_vector_type(16))) float  f32x16;  // 32x32 acc

__device__ __forceinline__ unsigned short bf16rn(float x){
  unsigned u = __float_as_uint(x);
  unsigned r = u + 0x7fffu + ((u>>16)&1u);
  return (unsigned short)(r>>16);
}
__device__ __forceinline__ float bf2f(unsigned short h){
  return __uint_as_float(((unsigned)h)<<16);
}

// ---------------------------------------------------------------- setup
__global__ void k_misc(const float* __restrict__ Vc, float* __restrict__ V,
                       const float* __restrict__ W, float* __restrict__ Ws){
  int t = threadIdx.x;
  if(blockIdx.x < 4){
    int i = blockIdx.x*256 + t;
    float4 v = ((const float4*)Vc)[i];
    float mx = fmaxf(fmaxf(v.x,v.y), fmaxf(v.z,v.w));
    float e0=__expf(v.x-mx), e1=__expf(v.y-mx), e2=__expf(v.z-mx), e3=__expf(v.w-mx);
    float is = 1.f/(e0+e1+e2+e3);
    ((float4*)V)[i] = make_float4(e0*is, e1*is, e2*is, e3*is);
  } else {
    int idx = (blockIdx.x-4)*256 + t;
    int i = idx>>10, j = idx&1023;
    float v = 0.f;
    if(i != j){
      float w = (i>j) ? W[i*1024+j] : W[j*1024+i];
      v = 1.f/(1.f+__expf(-w));
    }
    Ws[idx]=v;
  }
}

__global__ void k_pr_y(const float* __restrict__ V, const int* __restrict__ x,
                       float* __restrict__ PrInv, float* __restrict__ y){
  int b = blockIdx.x, t = threadIdx.x;
  __shared__ float red[256];
  float acc = 0.f;
  for(int i=t; i<1024; i+=256){
    int xv = x[b*1024+i];
    float pr = V[i*4+xv];
    PrInv[b*1024+i] = 1.f/pr;
    acc += logf(pr + 1e-7f);
  }
  red[t]=acc; __syncthreads();
  for(int s=128;s>0;s>>=1){ if(t<s) red[t]+=red[t+s]; __syncthreads(); }
  if(t==0) y[b]=red[0];
}

// ---------------------------------------------------------------- sinkhorn + WP
__global__ void __launch_bounds__(256) k_sinkhorn(
    const float* __restrict__ Ec, const float* __restrict__ V,
    const float* __restrict__ Ws, const float* __restrict__ PrInv,
    const int* __restrict__ x, float* __restrict__ mats,
    float* __restrict__ partial){
  int idx = blockIdx.x*256 + threadIdx.x;
  int i = idx>>10, j = idx&1023;
  if(i==0) return;
  int t = threadIdx.x;
  int lane = t & 63, wv = t >> 6;
  __shared__ float sE[256][17];
  float E[16];
  {
    const float4* p = (const float4*)(Ec + (size_t)idx*16);
    float4 q0=p[0], q1=p[1], q2=p[2], q3=p[3];
    E[0]=__expf(q0.x); E[1]=__expf(q0.y); E[2]=__expf(q0.z); E[3]=__expf(q0.w);
    E[4]=__expf(q1.x); E[5]=__expf(q1.y); E[6]=__expf(q1.z); E[7]=__expf(q1.w);
    E[8]=__expf(q2.x); E[9]=__expf(q2.y); E[10]=__expf(q2.z); E[11]=__expf(q2.w);
    E[12]=__expf(q3.x);E[13]=__expf(q3.y);E[14]=__expf(q3.z); E[15]=__expf(q3.w);
  }
  float s0=0.f;
  #pragma unroll
  for(int q=0;q<16;q++) s0+=E[q];
  float is0 = frcp(s0);
  #pragma unroll
  for(int q=0;q<16;q++) E[q]*=is0;
  float av[4], bv[4];
  {
    float4 va = ((const float4*)V)[i];
    av[0]=va.x; av[1]=va.y; av[2]=va.z; av[3]=va.w;
    float4 vb = ((const float4*)V)[j];
    bv[0]=vb.x; bv[1]=vb.y; bv[2]=vb.z; bv[3]=vb.w;
  }
  for(int it=0; it<NSINK; ++it){
    #pragma unroll
    for(int r=0;r<4;r++){
      float rs = E[4*r]+E[4*r+1]+E[4*r+2]+E[4*r+3];
      float sc = av[r]*frcp(rs+1e-7f);
      E[4*r]*=sc; E[4*r+1]*=sc; E[4*r+2]*=sc; E[4*r+3]*=sc;
    }
    #pragma unroll
    for(int c=0;c<4;c++){
      float cs = E[c]+E[4+c]+E[8+c]+E[12+c];
      float sc = bv[c]*frcp(cs+1e-7f);
      E[c]*=sc; E[4+c]*=sc; E[8+c]*=sc; E[12+c]*=sc;
    }
  }
  #pragma unroll
  for(int q=0;q<16;q++) sE[t][q] = fminf(fmaxf(E[q],0.f),1.f);
  float wsij = Ws[idx];
  for(int b=0;b<32;b++){
    int xi = x[b*1024+i];
    int xj = x[b*1024+j];
    float val = sE[t][(xi<<2)+xj] * wsij * PrInv[b*1024+i] * PrInv[b*1024+j];
    if(j!=0)
      mats[(size_t)(1+b)*MSZ + (size_t)(i-1)*1024 + (j-1)] = 1e-7f - val;
    float r = val;
    r += __shfl_down(r,32); r += __shfl_down(r,16); r += __shfl_down(r,8);
    r += __shfl_down(r,4);  r += __shfl_down(r,2);  r += __shfl_down(r,1);
    if(lane==0)
      partial[((size_t)b<<14) + ((size_t)(i-1)<<4) + ((blockIdx.x&3)<<2) + wv] = r;
  }
}

// ---------------------------------------------------------------- L0 build
__global__ void k_l0(const float* __restrict__ Ws, float* __restrict__ mats){
  int r = blockIdx.x, t = threadIdx.x;
  float* orow = mats + (size_t)r*1024;
  if(r == 1023){
    float4 o = make_float4(0.f,0.f,0.f,0.f);
    if(t==255) o.w = 1.f;
    ((float4*)orow)[t] = o;
    return;
  }
  const float* wrow = Ws + (size_t)(r+1)*1024;
  float4 v = ((const float4*)wrow)[t];
  __shared__ float red[256];
  red[t] = v.x+v.y+v.z+v.w;
  __syncthreads();
  for(int s=128;s>0;s>>=1){ if(t<s) red[t]+=red[t+s]; __syncthreads(); }
  float rs = red[0];
  float o[4];
  #pragma unroll
  for(int q=0;q<4;q++){
    int c = 4*t+q;
    if(c==r)          o[q] = rs + 1e-7f;
    else if(c < 1023) o[q] = 1e-7f - wrow[c+1];
    else              o[q] = 0.f;
  }
  ((float4*)orow)[t] = make_float4(o[0],o[1],o[2],o[3]);
}

__global__ void k_patch(float* __restrict__ mats, const float* __restrict__ partial){
  int m = blockIdx.y + 1;
  int r = blockIdx.x*256 + threadIdx.x;
  float* A = mats + (size_t)m*MSZ;
  A[(size_t)r*1024 + 1023] = (r==1023) ? 1.f : 0.f;
  if(r < 1023){
    A[(size_t)1023*1024 + r] = 0.f;
    const float* pp = partial + (((size_t)(m-1))<<14) + ((size_t)r<<4);
    float s = 0.f;
    #pragma unroll
    for(int q=0;q<16;q++) s += pp[q];
    A[(size_t)r*1024 + r] = s + 1e-7f;
  }
}

// ---------------------------------------------------------- 128x128 diag LU
// LU128 (LU64 + panels + Schur + LU64) then blocked inverse:
//   Uinv128 = [U11inv, -U11inv*U12*U22inv; 0, U22inv]   (same for L)
// T1 (REWORKED from R8, which spilled: x[64]+s[64] hit the 256-VGPR cap,
// WRITE_SIZE 92MB scratch, 988us): row-wise 64-triangle inverses with
// IN-PLACE writes — x[c] goes straight into LDS cell (lane,c) when final.
// Safe: row r of a triangle is only READ at iteration r; the write to
// (lane,c) happens at iteration c, at-or-after row lane's read in the
// iteration order (U ascending, c>=lane; L descending, c<lane).  Cross-wave
// reads of concurrently-written dead cells pollute only dead accumulators
// (4B LDS ops don't tear).  Live state = s[64] only.
// T2: off-diag products as two dense fp32 LDS GEMM passes.
__global__ void __launch_bounds__(256) k_diag(const float* __restrict__ mats_,
    unsigned short* __restrict__ UiH, unsigned short* __restrict__ UiL,
    unsigned short* __restrict__ LiH, unsigned short* __restrict__ LiL,
    float* __restrict__ logdet, int k, int inv){
  int m = blockIdx.x;
  const float* A = mats_ + (size_t)m*MSZ;
  int t = threadIdx.x, lane = t & 63, w = t >> 6;
  __shared__ float sm[128*128];   // 64 KB

  // load D = A[k:k+128, k:k+128]
  {
    int r = t >> 1, h = (t & 1) * 64;
    const float4* src = (const float4*)(A + (size_t)(k + r)*1024 + k + h);
    float4* dst = (float4*)&sm[r*128 + h];
    #pragma unroll
    for(int q=0;q<16;q++) dst[q] = src[q];
  }
  __syncthreads();

  float slog = 0.f;
  // ---- LU64 on D11 (wave 0, shuffle form)
  if(w==0){
    float row[64];
    #pragma unroll
    for(int q4=0;q4<16;q4++){
      float4 v = *(const float4*)&sm[lane*128 + 4*q4];
      row[4*q4]=v.x; row[4*q4+1]=v.y; row[4*q4+2]=v.z; row[4*q4+3]=v.w;
    }
    #pragma unroll
    for(int c=0;c<64;c++){
      float piv = __shfl(row[c], c);
      slog += logf(fabsf(piv));
      float ip = frcp(piv);
      bool below = lane > c;
      float lic = below ? row[c]*ip : 0.f;
      if(below) row[c] = lic;
      #pragma unroll
      for(int q=c+1;q<64;q++){
        float uq = __shfl(row[q], c);
        row[q] = fmaf(-lic, uq, row[q]);
      }
    }
    #pragma unroll
    for(int q=0;q<64;q++) sm[lane*128+q] = row[q];
  }
  __syncthreads();

  // ---- panel solves, saxpy form
  if(w==0){
    float s[64];
    #pragma unroll
    for(int q=0;q<64;q++) s[q]=0.f;
    #pragma unroll
    for(int r=0;r<64;r++){
      float xr = sm[r*128 + 64 + lane] - s[r];
      sm[r*128 + 64 + lane] = xr;
      #pragma unroll
      for(int c=r+1;c<64;c++)
        s[c] = fmaf(sm[c*128 + r], xr, s[c]);
    }
  } else if(w==1){
    float d[64], s[64];
    {
      const float4* src4 = (const float4*)&sm[(64+lane)*128];
      #pragma unroll
      for(int q=0;q<16;q++){
        float4 v=src4[q];
        d[4*q]=v.x; d[4*q+1]=v.y; d[4*q+2]=v.z; d[4*q+3]=v.w;
      }
    }
    #pragma unroll
    for(int q=0;q<64;q++) s[q]=0.f;
    #pragma unroll
    for(int c=0;c<64;c++){
      float xc = (d[c] - s[c]) * frcp(sm[c*128+c]);
      d[c] = xc;
      #pragma unroll
      for(int q=c+1;q<64;q++)
        s[q] = fmaf(sm[c*128+q], xc, s[q]);
    }
    {
      float4* dst4 = (float4*)&sm[(64+lane)*128];
      #pragma unroll
      for(int q=0;q<16;q++)
        dst4[q] = make_float4(d[4*q],d[4*q+1],d[4*q+2],d[4*q+3]);
    }
  }
  __syncthreads();

  // ---- Schur: D22 -= L21*U12
  {
    int j = lane;
    #pragma unroll
    for(int ii=0; ii<16; ii++){
      int i = w*16 + ii;
      float acc2 = sm[(64+i)*128 + 64 + j];
      #pragma unroll
      for(int p=0;p<64;p+=4){
        float4 l4 = *(const float4*)&sm[(64+i)*128 + p];   // uniform
        acc2 = fmaf(-l4.x, sm[(p  )*128 + 64 + j], acc2);
        acc2 = fmaf(-l4.y, sm[(p+1)*128 + 64 + j], acc2);
        acc2 = fmaf(-l4.z, sm[(p+2)*128 + 64 + j], acc2);
        acc2 = fmaf(-l4.w, sm[(p+3)*128 + 64 + j], acc2);
      }
      sm[(64+i)*128 + 64 + j] = acc2;
    }
  }
  __syncthreads();

  // ---- LU64 on updated D22 (wave 0)
  if(w==0){
    float row[64];
    #pragma unroll
    for(int q4=0;q4<16;q4++){
      float4 v = *(const float4*)&sm[(64+lane)*128 + 64 + 4*q4];
      row[4*q4]=v.x; row[4*q4+1]=v.y; row[4*q4+2]=v.z; row[4*q4+3]=v.w;
    }
    #pragma unroll
    for(int c=0;c<64;c++){
      float piv = __shfl(row[c], c);
      slog += logf(fabsf(piv));
      float ip = frcp(piv);
      bool below = lane > c;
      float lic = below ? row[c]*ip : 0.f;
      if(below) row[c] = lic;
      #pragma unroll
      for(int q=c+1;q<64;q++){
        float uq = __shfl(row[q], c);
        row[q] = fmaf(-lic, uq, row[q]);
      }
    }
    #pragma unroll
    for(int q=0;q<64;q++) sm[(64+lane)*128 + 64 + q] = row[q];
    if(lane==0){ if(k==0) logdet[m]=slog; else logdet[m]+=slog; }
  }
  __syncthreads();
  if(!inv) return;

  // ---- T1: in-place row-wise 64-triangle inverses (s[64] only).
  // w0: U11inv  w1: U22inv  (ascending c, write if c>=lane)
  // w2: L11inv  w3: L22inv  (descending c, write if c<lane)
  {
    float s[64];
    #pragma unroll
    for(int q=0;q<64;q++) s[q]=0.f;
    int b = (w&1)*64;
    if(w < 2){
      #pragma unroll
      for(int c=0;c<64;c++){
        float xc = (((c==lane)?1.f:0.f) - s[c]) * frcp(sm[(b+c)*128 + b + c]);
        #pragma unroll
        for(int q4=0;q4<16;q4++){
          float4 u = *(const float4*)&sm[(b+c)*128 + b + 4*q4];  // uniform quad
          s[4*q4  ] = fmaf(u.x, xc, s[4*q4  ]);
          s[4*q4+1] = fmaf(u.y, xc, s[4*q4+1]);
          s[4*q4+2] = fmaf(u.z, xc, s[4*q4+2]);
          s[4*q4+3] = fmaf(u.w, xc, s[4*q4+3]);
        }
        if(c >= lane) sm[(b+lane)*128 + b + c] = xc;   // upper incl diag
      }
    } else {
      #pragma unroll
      for(int c=63;c>=0;c--){
        float xc = ((c==lane)?1.f:0.f) - s[c];   // unit diag
        #pragma unroll
        for(int q4=0;q4<16;q4++){
          float4 u = *(const float4*)&sm[(b+c)*128 + b + 4*q4];  // uniform quad
          s[4*q4  ] = fmaf(u.x, xc, s[4*q4  ]);
          s[4*q4+1] = fmaf(u.y, xc, s[4*q4+1]);
          s[4*q4+2] = fmaf(u.z, xc, s[4*q4+2]);
          s[4*q4+3] = fmaf(u.w, xc, s[4*q4+3]);
        }
        if(c < lane) sm[(b+lane)*128 + b + c] = xc;    // strict lower
      }
    }
  }
  __syncthreads();

  // ---- T2 phase A: T = U12*U22inv -> Q12 ; S = L22inv*L21 -> Q21
  {
    float Ta[16], Sa[16];
    int j = lane;
    #pragma unroll
    for(int ii=0;ii<16;ii++){
      int i = w*16+ii;
      float au=0.f, al=0.f;
      #pragma unroll
      for(int p4=0;p4<16;p4++){
        float4 u12 = *(const float4*)&sm[i*128 + 64 + 4*p4];        // uniform
        float4 l22 = *(const float4*)&sm[(64+i)*128 + 64 + 4*p4];   // uniform
        #pragma unroll
        for(int e=0;e<4;e++){
          int p = 4*p4+e;
          float u12v = (e==0)?u12.x:(e==1)?u12.y:(e==2)?u12.z:u12.w;
          float l22v = (e==0)?l22.x:(e==1)?l22.y:(e==2)?l22.z:l22.w;
          float u22v = sm[(64+p)*128 + 64 + j];   // lanes consecutive
          au = fmaf(u12v, (p<=j)?u22v:0.f, au);
          float lsel = (p<i)?l22v:((p==i)?1.f:0.f);   // uniform select
          al = fmaf(lsel, sm[(64+p)*128 + j], al);    // L21 row p
        }
      }
      Ta[ii]=au; Sa[ii]=al;
    }
    __syncthreads();
    #pragma unroll
    for(int ii=0;ii<16;ii++){
      int i = w*16+ii;
      sm[i*128 + 64 + j] = Ta[ii];        // T -> Q12
      sm[(64+i)*128 + j] = Sa[ii];        // S -> Q21
    }
  }
  __syncthreads();

  // ---- T2 phase B: Q12 = -U11inv*T ; Q21 = -S*L11inv
  {
    float Bu[16], Bl[16];
    int j = lane;
    #pragma unroll
    for(int ii=0;ii<16;ii++){
      int i = w*16+ii;
      float au=0.f, al=0.f;
      #pragma unroll
      for(int p4=0;p4<16;p4++){
        float4 u11 = *(const float4*)&sm[i*128 + 4*p4];          // uniform
        float4 srow = *(const float4*)&sm[(64+i)*128 + 4*p4];    // uniform (S)
        #pragma unroll
        for(int e=0;e<4;e++){
          int p = 4*p4+e;
          float u11v = (e==0)?u11.x:(e==1)?u11.y:(e==2)?u11.z:u11.w;
          float sv   = (e==0)?srow.x:(e==1)?srow.y:(e==2)?srow.z:srow.w;
          au = fmaf((p>=i)?u11v:0.f, sm[p*128 + 64 + j], au);    // T row p
          float lv = sm[p*128 + j];                              // L11inv
          float lsel = (p>j)?lv:((p==j)?1.f:0.f);
          al = fmaf(sv, lsel, al);
        }
      }
      Bu[ii] = -au; Bl[ii] = -al;
    }
    __syncthreads();
    #pragma unroll
    for(int ii=0;ii<16;ii++){
      int i = w*16+ii;
      sm[i*128 + 64 + j] = Bu[ii];
      sm[(64+i)*128 + j] = Bl[ii];
    }
  }
  __syncthreads();

  // ---- emission.  t<128: Uinv col j=t.  t>=128: Linv row n=t-128.
  if(t < 128){
    int j = t;
    unsigned short* ph = UiH + (size_t)m*16384 + (size_t)j*128;
    unsigned short* pl = UiL + (size_t)m*16384 + (size_t)j*128;
    u16x8 H, L;
    #pragma unroll
    for(int r=0;r<128;r++){
      float v = (r<=j) ? sm[r*128+j] : 0.f;
      unsigned short h = bf16rn(v);
      H[r&7]=h; L[r&7]=bf16rn(v - bf2f(h));
      if((r&7)==7){ ((u16x8*)ph)[r>>3]=H; ((u16x8*)pl)[r>>3]=L; }
    }
  } else {
    int n = t - 128;
    unsigned short* ph = LiH + (size_t)m*16384 + (size_t)n*128;
    unsigned short* pl = LiL + (size_t)m*16384 + (size_t)n*128;
    #pragma unroll
    for(int q=0;q<16;q++){
      float4 u0 = *(const float4*)&sm[n*128 + 8*q];
      float4 u1 = *(const float4*)&sm[n*128 + 8*q + 4];
      float vv[8] = {u0.x,u0.y,u0.z,u0.w,u1.x,u1.y,u1.z,u1.w};
      u16x8 H, L;
      #pragma unroll
      for(int e=0;e<8;e++){
        int c = 8*q+e;
        float v = (c<n) ? vv[e] : ((c==n)?1.f:0.f);
        unsigned short h = bf16rn(v);
        H[e]=h; L[e]=bf16rn(v - bf2f(h));
      }
      ((u16x8*)ph)[q]=H; ((u16x8*)pl)[q]=L;
    }
  }
}

// ---------------------------------------------------------------- MFMA trsm
// K=128.  L21 = A21 * Uinv128 (blockIdx.x < nb), U12^T = A12^T * Linv128^T.
__global__ void __launch_bounds__(256) k_trsm(const float* __restrict__ mats_,
    const unsigned short* __restrict__ UiH, const unsigned short* __restrict__ UiL,
    const unsigned short* __restrict__ LiH, const unsigned short* __restrict__ LiL,
    unsigned short* __restrict__ Ah, unsigned short* __restrict__ Al,
    unsigned short* __restrict__ Bh, unsigned short* __restrict__ Bl,
    int k){
  int m = blockIdx.y;
  const float* A = mats_ + (size_t)m*MSZ;
  int rem = 1024 - (k+128);
  int nb = rem >> 7;
  bool aside = (int)blockIdx.x < nb;
  int t = threadIdx.x, lane = t&63;
  int r32 = lane&31, hi = lane>>5, wv = t>>6;
  int tile0 = (aside ? (int)blockIdx.x : (int)blockIdx.x - nb)*128 + wv*32;
  int rel  = tile0 + r32;

  const unsigned short* IH = (aside ? UiH : LiH) + (size_t)m*16384;
  const unsigned short* IL = (aside ? UiL : LiL) + (size_t)m*16384;

  f32x16 acc[4];
  #pragma unroll
  for(int ct=0;ct<4;ct++)
    #pragma unroll
    for(int q=0;q<16;q++) acc[ct][q]=0.f;

  #pragma unroll
  for(int kc=0;kc<8;kc++){
    float v[8];
    if(aside){
      const float* src = A + (size_t)(k+128+rel)*1024 + k + kc*16 + hi*8;
      float4 u0 = ((const float4*)src)[0];
      float4 u1 = ((const float4*)src)[1];
      v[0]=u0.x; v[1]=u0.y; v[2]=u0.z; v[3]=u0.w;
      v[4]=u1.x; v[5]=u1.y; v[6]=u1.z; v[7]=u1.w;
    } else {
      const float* src = A + (size_t)(k + kc*16 + hi*8)*1024 + (k+128+rel);
      #pragma unroll
      for(int e=0;e<8;e++) v[e] = src[(size_t)e*1024];
    }
    bfrag ah, al;
    #pragma unroll
    for(int e=0;e<8;e++){
      unsigned short h = bf16rn(v[e]);
      ah[e] = (short)h;
      al[e] = (short)bf16rn(v[e] - bf2f(h));
    }
    #pragma unroll
    for(int ct=0;ct<4;ct++){
      bfrag bh = *(const bfrag*)(IH + (size_t)(ct*32+r32)*128 + kc*16 + hi*8);
      bfrag bl = *(const bfrag*)(IL + (size_t)(ct*32+r32)*128 + kc*16 + hi*8);
      acc[ct] = __builtin_amdgcn_mfma_f32_32x32x16_bf16(ah, bh, acc[ct], 0,0,0);
      acc[ct] = __builtin_amdgcn_mfma_f32_32x32x16_bf16(ah, bl, acc[ct], 0,0,0);
      acc[ct] = __builtin_amdgcn_mfma_f32_32x32x16_bf16(al, bh, acc[ct], 0,0,0);
    }
  }

  unsigned short* PH = (aside ? Ah : Bh) + (size_t)m*PANSZ;
  unsigned short* PL = (aside ? Al : Bl) + (size_t)m*PANSZ;
  #pragma unroll
  for(int ct=0;ct<4;ct++){
    #pragma unroll
    for(int reg=0;reg<16;reg++){
      int crow = (reg&3) + ((reg>>2)<<3) + (hi<<2);
      int r = tile0 + crow;
      float v = acc[ct][reg];
      unsigned short h = bf16rn(v);
      size_t off = (size_t)r*128 + ct*32 + r32;
      PH[off] = h;
      PL[off] = bf16rn(v - bf2f(h));
    }
  }
}

// ------------------------------------------------------- MFMA split-bf16 Schur
// A22 -= L21 * U12, K=128 in 4 staged 32-chunks.  128x128 C tile, 4 waves.
__global__ void __launch_bounds__(256) k_gemm(float* __restrict__ mats,
    const unsigned short* __restrict__ Ah, const unsigned short* __restrict__ Al,
    const unsigned short* __restrict__ Bh, const unsigned short* __restrict__ Bl,
    int k){
  int m = blockIdx.z;
  float* A = mats + (size_t)m*MSZ;
  int i0rel = blockIdx.y*128;
  int j0rel = blockIdx.x*128;
  __shared__ unsigned short As[2][4096];   // [hi/lo][row*32 + swz(koct)*8]
  __shared__ unsigned short Bs[2][4096];
  int t = threadIdx.x;
  int lane = t & 63, wvi = t >> 6;
  int wr = wvi >> 1, wc = wvi & 1;

  const unsigned short* pAh = Ah + (size_t)m*PANSZ;
  const unsigned short* pAl = Al + (size_t)m*PANSZ;
  const unsigned short* pBh = Bh + (size_t)m*PANSZ;
  const unsigned short* pBl = Bl + (size_t)m*PANSZ;

  int ldsOff[2];
  size_t offA[2], offB[2];
  #pragma unroll
  for(int p=0;p<2;p++){
    int c = t + 256*p;
    int row = c>>2, koct = c&3;
    ldsOff[p] = row*32 + ((koct ^ ((row>>1)&3))<<3);
    offA[p] = (size_t)(i0rel+row)*128 + koct*8;
    offB[p] = (size_t)(j0rel+row)*128 + koct*8;
  }

  #pragma unroll
  for(int p=0;p<2;p++){
    u16x8 a0 = *(const u16x8*)(pAh + offA[p]);
    u16x8 a1 = *(const u16x8*)(pAl + offA[p]);
    u16x8 b0 = *(const u16x8*)(pBh + offB[p]);
    u16x8 b1 = *(const u16x8*)(pBl + offB[p]);
    *(u16x8*)&As[0][ldsOff[p]] = a0;
    *(u16x8*)&As[1][ldsOff[p]] = a1;
    *(u16x8*)&Bs[0][ldsOff[p]] = b0;
    *(u16x8*)&Bs[1][ldsOff[p]] = b1;
  }
  u16x8 p1[8];
  #pragma unroll
  for(int p=0;p<2;p++){
    p1[4*p+0] = *(const u16x8*)(pAh + offA[p] + 32);
    p1[4*p+1] = *(const u16x8*)(pAl + offA[p] + 32);
    p1[4*p+2] = *(const u16x8*)(pBh + offB[p] + 32);
    p1[4*p+3] = *(const u16x8*)(pBl + offB[p] + 32);
  }
  __syncthreads();

  f32x16 acc[2][2];
  #pragma unroll
  for(int rt=0;rt<2;rt++)
    #pragma unroll
    for(int ct=0;ct<2;ct++)
      #pragma unroll
      for(int q=0;q<16;q++) acc[rt][ct][q] = 0.f;

  int kgrp = lane >> 5;
  #pragma unroll
  for(int st=0; st<4; st++){
    #pragma unroll
    for(int kc=0;kc<2;kc++){
      int koct = kc*2 + kgrp;
      bfrag ah[2], al[2], bh[2], bl[2];
      #pragma unroll
      for(int rt=0;rt<2;rt++){
        int row = wr*64 + rt*32 + (lane&31);
        int ad = row*32 + ((koct ^ ((row>>1)&3))<<3);
        ah[rt] = *(const bfrag*)&As[0][ad];
        al[rt] = *(const bfrag*)&As[1][ad];
      }
      #pragma unroll
      for(int ct=0;ct<2;ct++){
        int col = wc*64 + ct*32 + (lane&31);
        int ad = col*32 + ((koct ^ ((col>>1)&3))<<3);
        bh[ct] = *(const bfrag*)&Bs[0][ad];
        bl[ct] = *(const bfrag*)&Bs[1][ad];
      }
      #pragma unroll
      for(int rt=0;rt<2;rt++)
        #pragma unroll
        for(int ct=0;ct<2;ct++){
          acc[rt][ct] = __builtin_amdgcn_mfma_f32_32x32x16_bf16(ah[rt], bh[ct], acc[rt][ct], 0,0,0);
          acc[rt][ct] = __builtin_amdgcn_mfma_f32_32x32x16_bf16(ah[rt], bl[ct], acc[rt][ct], 0,0,0);
          acc[rt][ct] = __builtin_amdgcn_mfma_f32_32x32x16_bf16(al[rt], bh[ct], acc[rt][ct], 0,0,0);
        }
    }
    if(st<3){
      __syncthreads();
      #pragma unroll
      for(int p=0;p<2;p++){
        *(u16x8*)&As[0][ldsOff[p]] = p1[4*p+0];
        *(u16x8*)&As[1][ldsOff[p]] = p1[4*p+1];
        *(u16x8*)&Bs[0][ldsOff[p]] = p1[4*p+2];
        *(u16x8*)&Bs[1][ldsOff[p]] = p1[4*p+3];
      }
      if(st<2){
        #pragma unroll
        for(int p=0;p<2;p++){
          p1[4*p+0] = *(const u16x8*)(pAh + offA[p] + (st+2)*32);
          p1[4*p+1] = *(const u16x8*)(pAl + offA[p] + (st+2)*32);
          p1[4*p+2] = *(const u16x8*)(pBh + offB[p] + (st+2)*32);
          p1[4*p+3] = *(const u16x8*)(pBl + offB[p] + (st+2)*32);
        }
      }
      __syncthreads();
    }
  }

  int r0 = k + 128;
  #pragma unroll
  for(int rt=0;rt<2;rt++){
    int rowblk = i0rel + wr*64 + rt*32;
    #pragma unroll
    for(int ct=0;ct<2;ct++){
      int colblk = j0rel + wc*64 + ct*32;
      int col = r0 + colblk + (lane&31);
      int rbase = r0 + rowblk + ((lane>>5)<<2);
      #pragma unroll
      for(int reg=0;reg<16;reg++){
        int row = rbase + (reg&3) + ((reg>>2)<<3);
        float* pc = A + (size_t)row*1024 + col;
        *pc -= acc[rt][ct][reg];
      }
    }
  }
}

__global__ void k_final(const float* __restrict__ y, const float* __restrict__ logdet,
                        float* __restrict__ out){
  int b = threadIdx.x;
  if(b<32) out[b] = y[b] + logdet[1+b] - logdet[0];
}

// ---------------------------------------------------------------- launch
extern "C" void kernel_launch(void* const* d_in, const int* in_sizes, int n_in,
                              void* d_out, int out_size, void* d_ws, size_t ws_size,
                              hipStream_t stream){
  (void)in_sizes; (void)n_in; (void)out_size; (void)ws_size;
  const int*   x  = (const int*)d_in[0];
  const float* W  = (const float*)d_in[1];
  const float* Vc = (const float*)d_in[2];
  const float* Ec = (const float*)d_in[3];
  float* out = (float*)d_out;

  char* p = (char*)d_ws;
  auto alloc = [&](size_t bytes)->char*{ char* r = p; p += (bytes+255)&~(size_t)255; return r; };
  float* mats   = (float*)alloc((size_t)NMAT*MSZ*4);              // 138.4 MB
  float* Ws     = (float*)alloc(1048576ull*4);
  unsigned short* Ah = (unsigned short*)alloc((size_t)NMAT*PANSZ*2);
  unsigned short* Al = (unsigned short*)alloc((size_t)NMAT*PANSZ*2);
  unsigned short* Bh = (unsigned short*)alloc((size_t)NMAT*PANSZ*2);
  unsigned short* Bl = (unsigned short*)alloc((size_t)NMAT*PANSZ*2);
  unsigned short* UiH = (unsigned short*)alloc((size_t)NMAT*16384*2);  // 1 MB each
  unsigned short* UiL = (unsigned short*)alloc((size_t)NMAT*16384*2);
  unsigned short* LiH = (unsigned short*)alloc((size_t)NMAT*16384*2);
  unsigned short* LiL = (unsigned short*)alloc((size_t)NMAT*16384*2);
  float* V      = (float*)alloc(4096*4);
  float* PrInv  = (float*)alloc(32768*4);
  float* partial= (float*)alloc((size_t)32*16384*4);              // 2 MB
  float* y      = (float*)alloc(256);
  float* logdet = (float*)alloc(256);

  k_misc<<<4100,256,0,stream>>>(Vc, V, W, Ws);
  k_pr_y<<<32,256,0,stream>>>(V, x, PrInv, y);
  k_sinkhorn<<<4096,256,0,stream>>>(Ec, V, Ws, PrInv, x, mats, partial);
  k_l0<<<1024,256,0,stream>>>(Ws, mats);
  k_patch<<<dim3(4,32),256,0,stream>>>(mats, partial);

  k_diag<<<NMAT,256,0,stream>>>(mats, UiH,UiL,LiH,LiL, logdet, 0, 1);
  for(int s=0;s<7;s++){
    int k = 128*s;
    int rem = 1024 - (k+128);
    int nb = rem/128;
    k_trsm<<<dim3(2*nb,NMAT),256,0,stream>>>(mats, UiH,UiL,LiH,LiL, Ah,Al,Bh,Bl, k);
    k_gemm<<<dim3(nb,nb,NMAT),256,0,stream>>>(mats, Ah,Al,Bh,Bl, k);
    k_diag<<<NMAT,256,0,stream>>>(mats, UiH,UiL,LiH,LiL, logdet, k+128, (s<6)?1:0);
  }
  k_final<<<1,32,0,stream>>>(y, logdet, out);
}

// Round 10
// 2402.701 us; speedup vs baseline: 2.7889x; 2.3464x over previous
//
#include <hip/hip_runtime.h>
#include <math.h>

#define MSZ    1048576ull  // 1024*1024 elements per matrix slot
#define NMAT   33          // matrix 0 = L0, matrices 1..32 = per-batch L
#define PANSZ  114688      // 896*128 shorts per matrix per panel plane
#define NSINK  14

__device__ __forceinline__ float frcp(float x){ return __builtin_amdgcn_rcpf(x); }

typedef __attribute__((ext_vector_type(8)))  short  bfrag;   // 8 x bf16 (4 VGPR)
typedef __attribute__((ext_vector_type(8)))  unsigned short u16x8;
typedef __attribute__((ext_vector_type(16))) float  f32x16;  // 32x32 acc

__device__ __forceinline__ unsigned short bf16rn(float x){
  unsigned u = __float_as_uint(x);
  unsigned r = u + 0x7fffu + ((u>>16)&1u);
  return (unsigned short)(r>>16);
}
__device__ __forceinline__ float bf2f(unsigned short h){
  return __uint_as_float(((unsigned)h)<<16);
}

// ---------------------------------------------------------------- setup
__global__ void k_misc(const float* __restrict__ Vc, float* __restrict__ V,
                       const float* __restrict__ W, float* __restrict__ Ws){
  int t = threadIdx.x;
  if(blockIdx.x < 4){
    int i = blockIdx.x*256 + t;
    float4 v = ((const float4*)Vc)[i];
    float mx = fmaxf(fmaxf(v.x,v.y), fmaxf(v.z,v.w));
    float e0=__expf(v.x-mx), e1=__expf(v.y-mx), e2=__expf(v.z-mx), e3=__expf(v.w-mx);
    float is = 1.f/(e0+e1+e2+e3);
    ((float4*)V)[i] = make_float4(e0*is, e1*is, e2*is, e3*is);
  } else {
    int idx = (blockIdx.x-4)*256 + t;
    int i = idx>>10, j = idx&1023;
    float v = 0.f;
    if(i != j){
      float w = (i>j) ? W[i*1024+j] : W[j*1024+i];
      v = 1.f/(1.f+__expf(-w));
    }
    Ws[idx]=v;
  }
}

__global__ void k_pr_y(const float* __restrict__ V, const int* __restrict__ x,
                       float* __restrict__ PrInv, float* __restrict__ y){
  int b = blockIdx.x, t = threadIdx.x;
  __shared__ float red[256];
  float acc = 0.f;
  for(int i=t; i<1024; i+=256){
    int xv = x[b*1024+i];
    float pr = V[i*4+xv];
    PrInv[b*1024+i] = 1.f/pr;
    acc += logf(pr + 1e-7f);
  }
  red[t]=acc; __syncthreads();
  for(int s=128;s>0;s>>=1){ if(t<s) red[t]+=red[t+s]; __syncthreads(); }
  if(t==0) y[b]=red[0];
}

// ---------------------------------------------------------------- sinkhorn + WP
__global__ void __launch_bounds__(256) k_sinkhorn(
    const float* __restrict__ Ec, const float* __restrict__ V,
    const float* __restrict__ Ws, const float* __restrict__ PrInv,
    const int* __restrict__ x, float* __restrict__ mats,
    float* __restrict__ partial){
  int idx = blockIdx.x*256 + threadIdx.x;
  int i = idx>>10, j = idx&1023;
  if(i==0) return;
  int t = threadIdx.x;
  int lane = t & 63, wv = t >> 6;
  __shared__ float sE[256][17];
  float E[16];
  {
    const float4* p = (const float4*)(Ec + (size_t)idx*16);
    float4 q0=p[0], q1=p[1], q2=p[2], q3=p[3];
    E[0]=__expf(q0.x); E[1]=__expf(q0.y); E[2]=__expf(q0.z); E[3]=__expf(q0.w);
    E[4]=__expf(q1.x); E[5]=__expf(q1.y); E[6]=__expf(q1.z); E[7]=__expf(q1.w);
    E[8]=__expf(q2.x); E[9]=__expf(q2.y); E[10]=__expf(q2.z); E[11]=__expf(q2.w);
    E[12]=__expf(q3.x);E[13]=__expf(q3.y);E[14]=__expf(q3.z); E[15]=__expf(q3.w);
  }
  float s0=0.f;
  #pragma unroll
  for(int q=0;q<16;q++) s0+=E[q];
  float is0 = frcp(s0);
  #pragma unroll
  for(int q=0;q<16;q++) E[q]*=is0;
  float av[4], bv[4];
  {
    float4 va = ((const float4*)V)[i];
    av[0]=va.x; av[1]=va.y; av[2]=va.z; av[3]=va.w;
    float4 vb = ((const float4*)V)[j];
    bv[0]=vb.x; bv[1]=vb.y; bv[2]=vb.z; bv[3]=vb.w;
  }
  for(int it=0; it<NSINK; ++it){
    #pragma unroll
    for(int r=0;r<4;r++){
      float rs = E[4*r]+E[4*r+1]+E[4*r+2]+E[4*r+3];
      float sc = av[r]*frcp(rs+1e-7f);
      E[4*r]*=sc; E[4*r+1]*=sc; E[4*r+2]*=sc; E[4*r+3]*=sc;
    }
    #pragma unroll
    for(int c=0;c<4;c++){
      float cs = E[c]+E[4+c]+E[8+c]+E[12+c];
      float sc = bv[c]*frcp(cs+1e-7f);
      E[c]*=sc; E[4+c]*=sc; E[8+c]*=sc; E[12+c]*=sc;
    }
  }
  #pragma unroll
  for(int q=0;q<16;q++) sE[t][q] = fminf(fmaxf(E[q],0.f),1.f);
  float wsij = Ws[idx];
  for(int b=0;b<32;b++){
    int xi = x[b*1024+i];
    int xj = x[b*1024+j];
    float val = sE[t][(xi<<2)+xj] * wsij * PrInv[b*1024+i] * PrInv[b*1024+j];
    if(j!=0)
      mats[(size_t)(1+b)*MSZ + (size_t)(i-1)*1024 + (j-1)] = 1e-7f - val;
    float r = val;
    r += __shfl_down(r,32); r += __shfl_down(r,16); r += __shfl_down(r,8);
    r += __shfl_down(r,4);  r += __shfl_down(r,2);  r += __shfl_down(r,1);
    if(lane==0)
      partial[((size_t)b<<14) + ((size_t)(i-1)<<4) + ((blockIdx.x&3)<<2) + wv] = r;
  }
}

// ---------------------------------------------------------------- L0 build
__global__ void k_l0(const float* __restrict__ Ws, float* __restrict__ mats){
  int r = blockIdx.x, t = threadIdx.x;
  float* orow = mats + (size_t)r*1024;
  if(r == 1023){
    float4 o = make_float4(0.f,0.f,0.f,0.f);
    if(t==255) o.w = 1.f;
    ((float4*)orow)[t] = o;
    return;
  }
  const float* wrow = Ws + (size_t)(r+1)*1024;
  float4 v = ((const float4*)wrow)[t];
  __shared__ float red[256];
  red[t] = v.x+v.y+v.z+v.w;
  __syncthreads();
  for(int s=128;s>0;s>>=1){ if(t<s) red[t]+=red[t+s]; __syncthreads(); }
  float rs = red[0];
  float o[4];
  #pragma unroll
  for(int q=0;q<4;q++){
    int c = 4*t+q;
    if(c==r)          o[q] = rs + 1e-7f;
    else if(c < 1023) o[q] = 1e-7f - wrow[c+1];
    else              o[q] = 0.f;
  }
  ((float4*)orow)[t] = make_float4(o[0],o[1],o[2],o[3]);
}

__global__ void k_patch(float* __restrict__ mats, const float* __restrict__ partial){
  int m = blockIdx.y + 1;
  int r = blockIdx.x*256 + threadIdx.x;
  float* A = mats + (size_t)m*MSZ;
  A[(size_t)r*1024 + 1023] = (r==1023) ? 1.f : 0.f;
  if(r < 1023){
    A[(size_t)1023*1024 + r] = 0.f;
    const float* pp = partial + (((size_t)(m-1))<<14) + ((size_t)r<<4);
    float s = 0.f;
    #pragma unroll
    for(int q=0;q<16;q++) s += pp[q];
    A[(size_t)r*1024 + r] = s + 1e-7f;
  }
}

// ---------------------------------------------------------- 128x128 LU only
// Proven R6-R9 LU phases (LU64 + panels + Schur + LU64) + logdet; writes the
// LU factors back INTO the diag block of mats (dead region after this stage).
// Small kernel = isolated regalloc (the session's recurring lesson).
__global__ void __launch_bounds__(256) k_lu(float* __restrict__ mats_,
    float* __restrict__ logdet, int k){
  int m = blockIdx.x;
  float* A = mats_ + (size_t)m*MSZ;
  int t = threadIdx.x, lane = t & 63, w = t >> 6;
  __shared__ float sm[128*128];   // 64 KB

  {
    int r = t >> 1, h = (t & 1) * 64;
    const float4* src = (const float4*)(A + (size_t)(k + r)*1024 + k + h);
    float4* dst = (float4*)&sm[r*128 + h];
    #pragma unroll
    for(int q=0;q<16;q++) dst[q] = src[q];
  }
  __syncthreads();

  float slog = 0.f;
  // ---- LU64 on D11 (wave 0, shuffle form)
  if(w==0){
    float row[64];
    #pragma unroll
    for(int q4=0;q4<16;q4++){
      float4 v = *(const float4*)&sm[lane*128 + 4*q4];
      row[4*q4]=v.x; row[4*q4+1]=v.y; row[4*q4+2]=v.z; row[4*q4+3]=v.w;
    }
    #pragma unroll
    for(int c=0;c<64;c++){
      float piv = __shfl(row[c], c);
      slog += logf(fabsf(piv));
      float ip = frcp(piv);
      bool below = lane > c;
      float lic = below ? row[c]*ip : 0.f;
      if(below) row[c] = lic;
      #pragma unroll
      for(int q=c+1;q<64;q++){
        float uq = __shfl(row[q], c);
        row[q] = fmaf(-lic, uq, row[q]);
      }
    }
    #pragma unroll
    for(int q=0;q<64;q++) sm[lane*128+q] = row[q];
  }
  __syncthreads();

  // ---- panel solves, saxpy form
  if(w==0){
    float s[64];
    #pragma unroll
    for(int q=0;q<64;q++) s[q]=0.f;
    #pragma unroll
    for(int r=0;r<64;r++){
      float xr = sm[r*128 + 64 + lane] - s[r];
      sm[r*128 + 64 + lane] = xr;
      #pragma unroll
      for(int c=r+1;c<64;c++)
        s[c] = fmaf(sm[c*128 + r], xr, s[c]);
    }
  } else if(w==1){
    float d[64], s[64];
    {
      const float4* src4 = (const float4*)&sm[(64+lane)*128];
      #pragma unroll
      for(int q=0;q<16;q++){
        float4 v=src4[q];
        d[4*q]=v.x; d[4*q+1]=v.y; d[4*q+2]=v.z; d[4*q+3]=v.w;
      }
    }
    #pragma unroll
    for(int q=0;q<64;q++) s[q]=0.f;
    #pragma unroll
    for(int c=0;c<64;c++){
      float xc = (d[c] - s[c]) * frcp(sm[c*128+c]);
      d[c] = xc;
      #pragma unroll
      for(int q=c+1;q<64;q++)
        s[q] = fmaf(sm[c*128+q], xc, s[q]);
    }
    {
      float4* dst4 = (float4*)&sm[(64+lane)*128];
      #pragma unroll
      for(int q=0;q<16;q++)
        dst4[q] = make_float4(d[4*q],d[4*q+1],d[4*q+2],d[4*q+3]);
    }
  }
  __syncthreads();

  // ---- Schur: D22 -= L21*U12
  {
    int j = lane;
    #pragma unroll
    for(int ii=0; ii<16; ii++){
      int i = w*16 + ii;
      float acc2 = sm[(64+i)*128 + 64 + j];
      #pragma unroll
      for(int p=0;p<64;p+=4){
        float4 l4 = *(const float4*)&sm[(64+i)*128 + p];   // uniform
        acc2 = fmaf(-l4.x, sm[(p  )*128 + 64 + j], acc2);
        acc2 = fmaf(-l4.y, sm[(p+1)*128 + 64 + j], acc2);
        acc2 = fmaf(-l4.z, sm[(p+2)*128 + 64 + j], acc2);
        acc2 = fmaf(-l4.w, sm[(p+3)*128 + 64 + j], acc2);
      }
      sm[(64+i)*128 + 64 + j] = acc2;
    }
  }
  __syncthreads();

  // ---- LU64 on updated D22 (wave 0)
  if(w==0){
    float row[64];
    #pragma unroll
    for(int q4=0;q4<16;q4++){
      float4 v = *(const float4*)&sm[(64+lane)*128 + 64 + 4*q4];
      row[4*q4]=v.x; row[4*q4+1]=v.y; row[4*q4+2]=v.z; row[4*q4+3]=v.w;
    }
    #pragma unroll
    for(int c=0;c<64;c++){
      float piv = __shfl(row[c], c);
      slog += logf(fabsf(piv));
      float ip = frcp(piv);
      bool below = lane > c;
      float lic = below ? row[c]*ip : 0.f;
      if(below) row[c] = lic;
      #pragma unroll
      for(int q=c+1;q<64;q++){
        float uq = __shfl(row[q], c);
        row[q] = fmaf(-lic, uq, row[q]);
      }
    }
    #pragma unroll
    for(int q=0;q<64;q++) sm[(64+lane)*128 + 64 + q] = row[q];
    if(lane==0){ if(k==0) logdet[m]=slog; else logdet[m]+=slog; }
  }
  __syncthreads();

  // ---- writeback LU into the (dead) diag block of mats
  {
    int r = t >> 1, h = (t & 1) * 64;
    float4* dst = (float4*)(A + (size_t)(k + r)*1024 + k + h);
    const float4* src = (const float4*)&sm[r*128 + h];
    #pragma unroll
    for(int q=0;q<16;q++) dst[q] = src[q];
  }
}

// ---------------------------------------------------------- blocked inverse
// Reads the LU block from mats (written by k_lu).  T1: in-place row-wise
// 64-triangle inverses (s[64] only, full unroll for static indexing).
// T2 (REWORKED from R8/R9, which spilled: Ta[16]/Sa[16] live across a fully
// unrolled 16-iter GEMM pass blew past 256 VGPR -> 116MB scratch): phase A
// writes into fresh LDS buffers TT/SS (read-set sm, write-set TT/SS disjoint
// -> unroll 1, 2 live scalars).  Phase B reads {sm-UL, TT, SS}, writes
// {sm-UR, sm-LL} (disjoint) -> direct writes, unroll 1.  96KB LDS (1 blk/CU;
// kernel is only 33 blocks).  Emission as R9.
__global__ void __launch_bounds__(256) k_inv(const float* __restrict__ mats_,
    unsigned short* __restrict__ UiH, unsigned short* __restrict__ UiL,
    unsigned short* __restrict__ LiH, unsigned short* __restrict__ LiL,
    int k){
  int m = blockIdx.x;
  const float* A = mats_ + (size_t)m*MSZ;
  int t = threadIdx.x, lane = t & 63, w = t >> 6;
  __shared__ float sm[128*128];   // 64 KB
  __shared__ float TT[64*64];     // 16 KB
  __shared__ float SS[64*64];     // 16 KB

  {
    int r = t >> 1, h = (t & 1) * 64;
    const float4* src = (const float4*)(A + (size_t)(k + r)*1024 + k + h);
    float4* dst = (float4*)&sm[r*128 + h];
    #pragma unroll
    for(int q=0;q<16;q++) dst[q] = src[q];
  }
  __syncthreads();

  // ---- T1: in-place row-wise 64-triangle inverses (s[64] only).
  // w0: U11inv  w1: U22inv  (ascending c, write if c>=lane)
  // w2: L11inv  w3: L22inv  (descending c, write if c<lane)
  {
    float s[64];
    #pragma unroll
    for(int q=0;q<64;q++) s[q]=0.f;
    int b = (w&1)*64;
    if(w < 2){
      #pragma unroll
      for(int c=0;c<64;c++){
        float xc = (((c==lane)?1.f:0.f) - s[c]) * frcp(sm[(b+c)*128 + b + c]);
        #pragma unroll
        for(int q4=0;q4<16;q4++){
          float4 u = *(const float4*)&sm[(b+c)*128 + b + 4*q4];  // uniform quad
          s[4*q4  ] = fmaf(u.x, xc, s[4*q4  ]);
          s[4*q4+1] = fmaf(u.y, xc, s[4*q4+1]);
          s[4*q4+2] = fmaf(u.z, xc, s[4*q4+2]);
          s[4*q4+3] = fmaf(u.w, xc, s[4*q4+3]);
        }
        if(c >= lane) sm[(b+lane)*128 + b + c] = xc;   // upper incl diag
      }
    } else {
      #pragma unroll
      for(int c=63;c>=0;c--){
        float xc = ((c==lane)?1.f:0.f) - s[c];   // unit diag
        #pragma unroll
        for(int q4=0;q4<16;q4++){
          float4 u = *(const float4*)&sm[(b+c)*128 + b + 4*q4];  // uniform quad
          s[4*q4  ] = fmaf(u.x, xc, s[4*q4  ]);
          s[4*q4+1] = fmaf(u.y, xc, s[4*q4+1]);
          s[4*q4+2] = fmaf(u.z, xc, s[4*q4+2]);
          s[4*q4+3] = fmaf(u.w, xc, s[4*q4+3]);
        }
        if(c < lane) sm[(b+lane)*128 + b + c] = xc;    // strict lower
      }
    }
  }
  __syncthreads();

  // ---- T2 phase A: TT = U12*U22inv ; SS = L22inv*L21   (reads sm only)
  {
    int j = lane;
    #pragma unroll 1
    for(int ii=0;ii<16;ii++){
      int i = w*16+ii;
      float au=0.f, al=0.f;
      #pragma unroll
      for(int p4=0;p4<16;p4++){
        float4 u12 = *(const float4*)&sm[i*128 + 64 + 4*p4];        // uniform
        float4 l22 = *(const float4*)&sm[(64+i)*128 + 64 + 4*p4];   // uniform
        #pragma unroll
        for(int e=0;e<4;e++){
          int p = 4*p4+e;
          float u12v = (e==0)?u12.x:(e==1)?u12.y:(e==2)?u12.z:u12.w;
          float l22v = (e==0)?l22.x:(e==1)?l22.y:(e==2)?l22.z:l22.w;
          float u22v = sm[(64+p)*128 + 64 + j];   // lanes consecutive
          au = fmaf(u12v, (p<=j)?u22v:0.f, au);
          float lsel = (p<i)?l22v:((p==i)?1.f:0.f);   // uniform select
          al = fmaf(lsel, sm[(64+p)*128 + j], al);    // L21 row p
        }
      }
      TT[i*64 + j] = au;
      SS[i*64 + j] = al;
    }
  }
  __syncthreads();

  // ---- T2 phase B: sm_UR = -U11inv*TT ; sm_LL = -SS*L11inv
  // reads {sm upper-left, TT, SS}; writes {sm UR, sm LL} -> disjoint.
  {
    int j = lane;
    #pragma unroll 1
    for(int ii=0;ii<16;ii++){
      int i = w*16+ii;
      float au=0.f, al=0.f;
      #pragma unroll
      for(int p4=0;p4<16;p4++){
        float4 u11 = *(const float4*)&sm[i*128 + 4*p4];       // uniform
        float4 srow = *(const float4*)&SS[i*64 + 4*p4];       // uniform
        #pragma unroll
        for(int e=0;e<4;e++){
          int p = 4*p4+e;
          float u11v = (e==0)?u11.x:(e==1)?u11.y:(e==2)?u11.z:u11.w;
          float sv   = (e==0)?srow.x:(e==1)?srow.y:(e==2)?srow.z:srow.w;
          au = fmaf((p>=i)?u11v:0.f, TT[p*64 + j], au);
          float lv = sm[p*128 + j];                           // L11inv
          float lsel = (p>j)?lv:((p==j)?1.f:0.f);
          al = fmaf(sv, lsel, al);
        }
      }
      sm[i*128 + 64 + j]   = -au;
      sm[(64+i)*128 + j]   = -al;
    }
  }
  __syncthreads();

  // ---- emission.  t<128: Uinv col j=t.  t>=128: Linv row n=t-128.
  if(t < 128){
    int j = t;
    unsigned short* ph = UiH + (size_t)m*16384 + (size_t)j*128;
    unsigned short* pl = UiL + (size_t)m*16384 + (size_t)j*128;
    u16x8 H, L;
    #pragma unroll
    for(int r=0;r<128;r++){
      float v = (r<=j) ? sm[r*128+j] : 0.f;
      unsigned short h = bf16rn(v);
      H[r&7]=h; L[r&7]=bf16rn(v - bf2f(h));
      if((r&7)==7){ ((u16x8*)ph)[r>>3]=H; ((u16x8*)pl)[r>>3]=L; }
    }
  } else {
    int n = t - 128;
    unsigned short* ph = LiH + (size_t)m*16384 + (size_t)n*128;
    unsigned short* pl = LiL + (size_t)m*16384 + (size_t)n*128;
    #pragma unroll
    for(int q=0;q<16;q++){
      float4 u0 = *(const float4*)&sm[n*128 + 8*q];
      float4 u1 = *(const float4*)&sm[n*128 + 8*q + 4];
      float vv[8] = {u0.x,u0.y,u0.z,u0.w,u1.x,u1.y,u1.z,u1.w};
      u16x8 H, L;
      #pragma unroll
      for(int e=0;e<8;e++){
        int c = 8*q+e;
        float v = (c<n) ? vv[e] : ((c==n)?1.f:0.f);
        unsigned short h = bf16rn(v);
        H[e]=h; L[e]=bf16rn(v - bf2f(h));
      }
      ((u16x8*)ph)[q]=H; ((u16x8*)pl)[q]=L;
    }
  }
}

// ---------------------------------------------------------------- MFMA trsm
// K=128.  L21 = A21 * Uinv128 (blockIdx.x < nb), U12^T = A12^T * Linv128^T.
__global__ void __launch_bounds__(256) k_trsm(const float* __restrict__ mats_,
    const unsigned short* __restrict__ UiH, const unsigned short* __restrict__ UiL,
    const unsigned short* __restrict__ LiH, const unsigned short* __restrict__ LiL,
    unsigned short* __restrict__ Ah, unsigned short* __restrict__ Al,
    unsigned short* __restrict__ Bh, unsigned short* __restrict__ Bl,
    int k){
  int m = blockIdx.y;
  const float* A = mats_ + (size_t)m*MSZ;
  int rem = 1024 - (k+128);
  int nb = rem >> 7;
  bool aside = (int)blockIdx.x < nb;
  int t = threadIdx.x, lane = t&63;
  int r32 = lane&31, hi = lane>>5, wv = t>>6;
  int tile0 = (aside ? (int)blockIdx.x : (int)blockIdx.x - nb)*128 + wv*32;
  int rel  = tile0 + r32;

  const unsigned short* IH = (aside ? UiH : LiH) + (size_t)m*16384;
  const unsigned short* IL = (aside ? UiL : LiL) + (size_t)m*16384;

  f32x16 acc[4];
  #pragma unroll
  for(int ct=0;ct<4;ct++)
    #pragma unroll
    for(int q=0;q<16;q++) acc[ct][q]=0.f;

  #pragma unroll
  for(int kc=0;kc<8;kc++){
    float v[8];
    if(aside){
      const float* src = A + (size_t)(k+128+rel)*1024 + k + kc*16 + hi*8;
      float4 u0 = ((const float4*)src)[0];
      float4 u1 = ((const float4*)src)[1];
      v[0]=u0.x; v[1]=u0.y; v[2]=u0.z; v[3]=u0.w;
      v[4]=u1.x; v[5]=u1.y; v[6]=u1.z; v[7]=u1.w;
    } else {
      const float* src = A + (size_t)(k + kc*16 + hi*8)*1024 + (k+128+rel);
      #pragma unroll
      for(int e=0;e<8;e++) v[e] = src[(size_t)e*1024];
    }
    bfrag ah, al;
    #pragma unroll
    for(int e=0;e<8;e++){
      unsigned short h = bf16rn(v[e]);
      ah[e] = (short)h;
      al[e] = (short)bf16rn(v[e] - bf2f(h));
    }
    #pragma unroll
    for(int ct=0;ct<4;ct++){
      bfrag bh = *(const bfrag*)(IH + (size_t)(ct*32+r32)*128 + kc*16 + hi*8);
      bfrag bl = *(const bfrag*)(IL + (size_t)(ct*32+r32)*128 + kc*16 + hi*8);
      acc[ct] = __builtin_amdgcn_mfma_f32_32x32x16_bf16(ah, bh, acc[ct], 0,0,0);
      acc[ct] = __builtin_amdgcn_mfma_f32_32x32x16_bf16(ah, bl, acc[ct], 0,0,0);
      acc[ct] = __builtin_amdgcn_mfma_f32_32x32x16_bf16(al, bh, acc[ct], 0,0,0);
    }
  }

  unsigned short* PH = (aside ? Ah : Bh) + (size_t)m*PANSZ;
  unsigned short* PL = (aside ? Al : Bl) + (size_t)m*PANSZ;
  #pragma unroll
  for(int ct=0;ct<4;ct++){
    #pragma unroll
    for(int reg=0;reg<16;reg++){
      int crow = (reg&3) + ((reg>>2)<<3) + (hi<<2);
      int r = tile0 + crow;
      float v = acc[ct][reg];
      unsigned short h = bf16rn(v);
      size_t off = (size_t)r*128 + ct*32 + r32;
      PH[off] = h;
      PL[off] = bf16rn(v - bf2f(h));
    }
  }
}

// ------------------------------------------------------- MFMA split-bf16 Schur
// A22 -= L21 * U12, K=128 in 4 staged 32-chunks.  128x128 C tile, 4 waves.
__global__ void __launch_bounds__(256) k_gemm(float* __restrict__ mats,
    const unsigned short* __restrict__ Ah, const unsigned short* __restrict__ Al,
    const unsigned short* __restrict__ Bh, const unsigned short* __restrict__ Bl,
    int k){
  int m = blockIdx.z;
  float* A = mats + (size_t)m*MSZ;
  int i0rel = blockIdx.y*128;
  int j0rel = blockIdx.x*128;
  __shared__ unsigned short As[2][4096];   // [hi/lo][row*32 + swz(koct)*8]
  __shared__ unsigned short Bs[2][4096];
  int t = threadIdx.x;
  int lane = t & 63, wvi = t >> 6;
  int wr = wvi >> 1, wc = wvi & 1;

  const unsigned short* pAh = Ah + (size_t)m*PANSZ;
  const unsigned short* pAl = Al + (size_t)m*PANSZ;
  const unsigned short* pBh = Bh + (size_t)m*PANSZ;
  const unsigned short* pBl = Bl + (size_t)m*PANSZ;

  int ldsOff[2];
  size_t offA[2], offB[2];
  #pragma unroll
  for(int p=0;p<2;p++){
    int c = t + 256*p;
    int row = c>>2, koct = c&3;
    ldsOff[p] = row*32 + ((koct ^ ((row>>1)&3))<<3);
    offA[p] = (size_t)(i0rel+row)*128 + koct*8;
    offB[p] = (size_t)(j0rel+row)*128 + koct*8;
  }

  #pragma unroll
  for(int p=0;p<2;p++){
    u16x8 a0 = *(const u16x8*)(pAh + offA[p]);
    u16x8 a1 = *(const u16x8*)(pAl + offA[p]);
    u16x8 b0 = *(const u16x8*)(pBh + offB[p]);
    u16x8 b1 = *(const u16x8*)(pBl + offB[p]);
    *(u16x8*)&As[0][ldsOff[p]] = a0;
    *(u16x8*)&As[1][ldsOff[p]] = a1;
    *(u16x8*)&Bs[0][ldsOff[p]] = b0;
    *(u16x8*)&Bs[1][ldsOff[p]] = b1;
  }
  u16x8 p1[8];
  #pragma unroll
  for(int p=0;p<2;p++){
    p1[4*p+0] = *(const u16x8*)(pAh + offA[p] + 32);
    p1[4*p+1] = *(const u16x8*)(pAl + offA[p] + 32);
    p1[4*p+2] = *(const u16x8*)(pBh + offB[p] + 32);
    p1[4*p+3] = *(const u16x8*)(pBl + offB[p] + 32);
  }
  __syncthreads();

  f32x16 acc[2][2];
  #pragma unroll
  for(int rt=0;rt<2;rt++)
    #pragma unroll
    for(int ct=0;ct<2;ct++)
      #pragma unroll
      for(int q=0;q<16;q++) acc[rt][ct][q] = 0.f;

  int kgrp = lane >> 5;
  #pragma unroll
  for(int st=0; st<4; st++){
    #pragma unroll
    for(int kc=0;kc<2;kc++){
      int koct = kc*2 + kgrp;
      bfrag ah[2], al[2], bh[2], bl[2];
      #pragma unroll
      for(int rt=0;rt<2;rt++){
        int row = wr*64 + rt*32 + (lane&31);
        int ad = row*32 + ((koct ^ ((row>>1)&3))<<3);
        ah[rt] = *(const bfrag*)&As[0][ad];
        al[rt] = *(const bfrag*)&As[1][ad];
      }
      #pragma unroll
      for(int ct=0;ct<2;ct++){
        int col = wc*64 + ct*32 + (lane&31);
        int ad = col*32 + ((koct ^ ((col>>1)&3))<<3);
        bh[ct] = *(const bfrag*)&Bs[0][ad];
        bl[ct] = *(const bfrag*)&Bs[1][ad];
      }
      #pragma unroll
      for(int rt=0;rt<2;rt++)
        #pragma unroll
        for(int ct=0;ct<2;ct++){
          acc[rt][ct] = __builtin_amdgcn_mfma_f32_32x32x16_bf16(ah[rt], bh[ct], acc[rt][ct], 0,0,0);
          acc[rt][ct] = __builtin_amdgcn_mfma_f32_32x32x16_bf16(ah[rt], bl[ct], acc[rt][ct], 0,0,0);
          acc[rt][ct] = __builtin_amdgcn_mfma_f32_32x32x16_bf16(al[rt], bh[ct], acc[rt][ct], 0,0,0);
        }
    }
    if(st<3){
      __syncthreads();
      #pragma unroll
      for(int p=0;p<2;p++){
        *(u16x8*)&As[0][ldsOff[p]] = p1[4*p+0];
        *(u16x8*)&As[1][ldsOff[p]] = p1[4*p+1];
        *(u16x8*)&Bs[0][ldsOff[p]] = p1[4*p+2];
        *(u16x8*)&Bs[1][ldsOff[p]] = p1[4*p+3];
      }
      if(st<2){
        #pragma unroll
        for(int p=0;p<2;p++){
          p1[4*p+0] = *(const u16x8*)(pAh + offA[p] + (st+2)*32);
          p1[4*p+1] = *(const u16x8*)(pAl + offA[p] + (st+2)*32);
          p1[4*p+2] = *(const u16x8*)(pBh + offB[p] + (st+2)*32);
          p1[4*p+3] = *(const u16x8*)(pBl + offB[p] + (st+2)*32);
        }
      }
      __syncthreads();
    }
  }

  int r0 = k + 128;
  #pragma unroll
  for(int rt=0;rt<2;rt++){
    int rowblk = i0rel + wr*64 + rt*32;
    #pragma unroll
    for(int ct=0;ct<2;ct++){
      int colblk = j0rel + wc*64 + ct*32;
      int col = r0 + colblk + (lane&31);
      int rbase = r0 + rowblk + ((lane>>5)<<2);
      #pragma unroll
      for(int reg=0;reg<16;reg++){
        int row = rbase + (reg&3) + ((reg>>2)<<3);
        float* pc = A + (size_t)row*1024 + col;
        *pc -= acc[rt][ct][reg];
      }
    }
  }
}

__global__ void k_final(const float* __restrict__ y, const float* __restrict__ logdet,
                        float* __restrict__ out){
  int b = threadIdx.x;
  if(b<32) out[b] = y[b] + logdet[1+b] - logdet[0];
}

// ---------------------------------------------------------------- launch
extern "C" void kernel_launch(void* const* d_in, const int* in_sizes, int n_in,
                              void* d_out, int out_size, void* d_ws, size_t ws_size,
                              hipStream_t stream){
  (void)in_sizes; (void)n_in; (void)out_size; (void)ws_size;
  const int*   x  = (const int*)d_in[0];
  const float* W  = (const float*)d_in[1];
  const float* Vc = (const float*)d_in[2];
  const float* Ec = (const float*)d_in[3];
  float* out = (float*)d_out;

  char* p = (char*)d_ws;
  auto alloc = [&](size_t bytes)->char*{ char* r = p; p += (bytes+255)&~(size_t)255; return r; };
  float* mats   = (float*)alloc((size_t)NMAT*MSZ*4);              // 138.4 MB
  float* Ws     = (float*)alloc(1048576ull*4);
  unsigned short* Ah = (unsigned short*)alloc((size_t)NMAT*PANSZ*2);
  unsigned short* Al = (unsigned short*)alloc((size_t)NMAT*PANSZ*2);
  unsigned short* Bh = (unsigned short*)alloc((size_t)NMAT*PANSZ*2);
  unsigned short* Bl = (unsigned short*)alloc((size_t)NMAT*PANSZ*2);
  unsigned short* UiH = (unsigned short*)alloc((size_t)NMAT*16384*2);  // 1 MB each
  unsigned short* UiL = (unsigned short*)alloc((size_t)NMAT*16384*2);
  unsigned short* LiH = (unsigned short*)alloc((size_t)NMAT*16384*2);
  unsigned short* LiL = (unsigned short*)alloc((size_t)NMAT*16384*2);
  float* V      = (float*)alloc(4096*4);
  float* PrInv  = (float*)alloc(32768*4);
  float* partial= (float*)alloc((size_t)32*16384*4);              // 2 MB
  float* y      = (float*)alloc(256);
  float* logdet = (float*)alloc(256);

  k_misc<<<4100,256,0,stream>>>(Vc, V, W, Ws);
  k_pr_y<<<32,256,0,stream>>>(V, x, PrInv, y);
  k_sinkhorn<<<4096,256,0,stream>>>(Ec, V, Ws, PrInv, x, mats, partial);
  k_l0<<<1024,256,0,stream>>>(Ws, mats);
  k_patch<<<dim3(4,32),256,0,stream>>>(mats, partial);

  k_lu<<<NMAT,256,0,stream>>>(mats, logdet, 0);
  k_inv<<<NMAT,256,0,stream>>>(mats, UiH,UiL,LiH,LiL, 0);
  for(int s=0;s<7;s++){
    int k = 128*s;
    int rem = 1024 - (k+128);
    int nb = rem/128;
    k_trsm<<<dim3(2*nb,NMAT),256,0,stream>>>(mats, UiH,UiL,LiH,LiL, Ah,Al,Bh,Bl, k);
    k_gemm<<<dim3(nb,nb,NMAT),256,0,stream>>>(mats, Ah,Al,Bh,Bl, k);
    k_lu<<<NMAT,256,0,stream>>>(mats, logdet, k+128);
    if(s<6) k_inv<<<NMAT,256,0,stream>>>(mats, UiH,UiL,LiH,LiL, k+128);
  }
  k_final<<<1,32,0,stream>>>(y, logdet, out);
}